// Round 9
// baseline (561.593 us; speedup 1.0000x reference)
//
#include <hip/hip_runtime.h>
#include <hip/hip_bf16.h>
#include <math.h>

// ---- problem constants ----
constexpr int B_    = 4;
constexpr int C_    = 96;
constexpr int H_    = 256;
constexpr int W_    = 256;
constexpr int WS_   = 8;
constexpr int NH_   = 4;
constexpr int SHIFT_= 4;
constexpr int HD_   = 24;
constexpr int HW_   = H_*W_;
constexpr float EPS_   = 1e-6f;
constexpr float SCALE_ = 0.20412414523193150f; // 24^-0.5

using bf16   = __bf16;
using bf16x8 = __attribute__((ext_vector_type(8))) __bf16;
using bf16x4 = __attribute__((ext_vector_type(4))) __bf16;
using f32x4  = __attribute__((ext_vector_type(4))) float;

__device__ __forceinline__ f32x4 mfma16(bf16x8 a, bf16x8 b, f32x4 c) {
    return __builtin_amdgcn_mfma_f32_16x16x32_bf16(a, b, c, 0, 0, 0);
}

// ---- weight arena (bf16 elements) ----
constexpr int    WQ2_E   = 320*96;                        // per-head q|k|v|pad
constexpr int    WPR_E   = 96*96;
constexpr int    WF1_E   = 384*96;
constexpr int    WF2_E   = 96*384;
constexpr int    WSUM_E  = WQ2_E + WPR_E + WF1_E + WF2_E; // 113664
constexpr int    NBQ     = 320;
constexpr int    WBLKS   = (WSUM_E + NBQ + 255)/256;      // 446

__global__ __launch_bounds__(256) void prepw_kernel(
    const float* __restrict__ qkv_w, const float* __restrict__ qkv_b,
    const float* __restrict__ proj_w, const float* __restrict__ fc1w,
    const float* __restrict__ fc2w,
    bf16* __restrict__ warena, float* __restrict__ bq2)
{
    int i = blockIdx.x*256 + threadIdx.x;
    if (i < WQ2_E) {
        int R = i/96, c = i%96;
        int h = R/80, s = R%80;
        float v;
        if      (s < 24) v = qkv_w[(h*24+s)*96 + c] * SCALE_;
        else if (s < 48) v = qkv_w[(96 + h*24 + s-24)*96 + c];
        else if (s < 72) v = qkv_w[(192 + h*24 + s-48)*96 + c];
        else             v = 0.f;
        warena[i] = (bf16)v;
    } else if (i < WQ2_E + WPR_E) {
        warena[i] = (bf16)proj_w[i - WQ2_E];
    } else if (i < WQ2_E + WPR_E + WF1_E) {
        warena[i] = (bf16)fc1w[i - WQ2_E - WPR_E];
    } else if (i < WSUM_E) {
        warena[i] = (bf16)fc2w[i - WQ2_E - WPR_E - WF1_E];
    } else if (i < WSUM_E + NBQ) {
        int j = i - WSUM_E;
        int h = j/80, s = j%80;
        float v;
        if      (s < 24) v = qkv_b[h*24+s] * SCALE_;
        else if (s < 48) v = qkv_b[96 + h*24 + s-24];
        else if (s < 72) v = qkv_b[192 + h*24 + s-48];
        else             v = 0.f;
        bq2[j] = v;
    }
}

// ---- fused kernel LDS layout (bf16 element offsets) ----
// AXO [64][104] : x-bf16 -> ln1 (in place) -> attn-out -> proj-out -> h
// B0/B1: double-buffered per-head QKV: Q[64][40] | K[64][24] | V^T[24][72]
//        (K b-frag tail spills into same buffer's V: junk x 0)
// P  [64][72] : softmax output (single buffer; reused across heads)
// MLP: MY [64][104] then MG [64][136] overlay B0 region (dead after attn).
constexpr int AXO_E = 0;
constexpr int B0_E  = 6656;
constexpr int B1_E  = 12480;            // B0_E + 5824
constexpr int P_E   = 18304;            // B1_E + 5824
constexpr int MYG_E = 6656;             // MLP overlay (B0/B1/P dead)
constexpr int SM_E  = 22912;            // el = 45824 B -> 3 blocks/CU

__global__ __launch_bounds__(256, 3) void fused_kernel(
    const float* __restrict__ x,       // [B,C,H,W] f32
    const float* __restrict__ norm_w, const float* __restrict__ norm_b,
    const bf16*  __restrict__ wq2,     // [320][96] per-head q|k|v|pad
    const float* __restrict__ bq2,     // [320]
    const bf16*  __restrict__ wproj,   // [96][96]
    const float* __restrict__ proj_b,
    const float* __restrict__ rpb,     // [225][4] f32
    const float* __restrict__ n2w, const float* __restrict__ n2b,
    const bf16*  __restrict__ wfc1, const float* __restrict__ fc1b,
    const bf16*  __restrict__ wfc2, const float* __restrict__ fc2b,
    float* __restrict__ out)           // [B,C,H,W] f32
{
    __shared__ __align__(16) bf16 sm[SM_E];

    const int tid  = threadIdx.x;
    const int wave = tid >> 6, lane = tid & 63;
    const int l16  = lane & 15, quad = lane >> 4;
    const int t  = tid >> 2, qa = tid & 3;
    const int qrow0 = wave*16;

    const int blk = blockIdx.x;
    const int b   = blk >> 10;
    const int wid = blk & 1023;
    const int wh  = wid >> 5, ww = wid & 31;

    // ---- Phase A: gather window's x (f32 NCHW, shifted+wrapped) -> AXO bf16 ----
    #pragma unroll
    for (int it = 0; it < 6; ++it) {
        const int i2  = it*256 + tid;          // 0..1535
        const int c   = i2 >> 4;               // 0..95
        const int rem = i2 & 15;
        const int wi  = rem >> 1;
        const int wj4 = (rem & 1)*4;
        const int gh  = (wh*WS_ + wi + SHIFT_) & (H_-1);
        const int gw0 = (ww*WS_ + wj4 + SHIFT_) & (W_-1);  // 4-aligned, no 16B crossing
        f32x4 v4 = *(const f32x4*)(x + (size_t)(b*96 + c)*HW_ + gh*W_ + gw0);
        #pragma unroll
        for (int j = 0; j < 4; ++j)
            sm[AXO_E + (wi*8 + wj4 + j)*104 + c] = (bf16)v4[j];
    }
    __syncthreads();

    // ---- Phase B0: LN1 in place (thread-local rows); x kept in REGISTERS ----
    bf16x8 xreg[3];                    // this thread's 24 x channels (residual)
    {
        float v[24]; float mu = 0.f, ss = 0.f;
        #pragma unroll
        for (int k = 0; k < 3; ++k) {
            xreg[k] = *(const bf16x8*)&sm[AXO_E + t*104 + qa*24 + k*8];
            #pragma unroll
            for (int j = 0; j < 8; ++j) {
                v[k*8+j] = (float)xreg[k][j];
                mu += v[k*8+j]; ss += v[k*8+j]*v[k*8+j];
            }
        }
        mu += __shfl_xor(mu,1); mu += __shfl_xor(mu,2);
        ss += __shfl_xor(ss,1); ss += __shfl_xor(ss,2);
        mu *= (1.f/C_);
        float rstd = rsqrtf(ss*(1.f/C_) - mu*mu + EPS_);
        #pragma unroll
        for (int k = 0; k < 3; ++k) {
            bf16x8 ln8;
            #pragma unroll
            for (int j = 0; j < 8; ++j) {
                const int c = qa*24 + k*8 + j;
                ln8[j] = (bf16)((v[k*8+j]-mu)*rstd*norm_w[c] + norm_b[c]);
            }
            *(bf16x8*)&sm[AXO_E + t*104 + qa*24 + k*8] = ln8;
        }
    }
    __syncthreads();   // AXO now holds xln

    // zero Q pad cols 24..31 of BOTH buffers (QKV stores never touch them)
    if (tid < 128) {
        bf16x8 z = {};
        const int bb = (tid >> 6) ? B1_E : B0_E;
        *(bf16x8*)&sm[bb + (tid & 63)*40 + 24] = z;
    }

    // A-frags of LN'd x, kept in registers for all heads
    bf16x8 af[4][3];
    #pragma unroll
    for (int mt = 0; mt < 4; ++mt)
        #pragma unroll
        for (int kk = 0; kk < 3; ++kk)
            af[mt][kk] = *(const bf16x8*)&sm[AXO_E + (mt*16+l16)*104 + kk*32 + quad*8];

    // ---- hoisted mask/bias index precompute (head-invariant) ----
    int   rix[4][4];   // rpb row index * NH_
    float mb [4][4];   // 0 or -100 shift mask term
    #pragma unroll
    for (int kt = 0; kt < 4; ++kt) {
        const int key = kt*16 + l16;
        const int ki = key >> 3, kj = key & 7;
        const int labk = (((wh*8+ki) >= H_-WS_) + ((wh*8+ki) >= H_-SHIFT_))*3
                       +  ((ww*8+kj) >= W_-WS_) + ((ww*8+kj) >= W_-SHIFT_);
        #pragma unroll
        for (int r = 0; r < 4; ++r) {
            const int q = qrow0 + quad*4 + r;
            const int ti = q >> 3, tj = q & 7;
            const int labq = (((wh*8+ti) >= H_-WS_) + ((wh*8+ti) >= H_-SHIFT_))*3
                           +  ((ww*8+tj) >= W_-WS_) + ((ww*8+tj) >= W_-SHIFT_);
            rix[kt][r] = ((ti - ki + 7)*15 + (tj - kj + 7))*NH_;
            mb [kt][r] = (labk != labq) ? -100.f : 0.f;
        }
    }

    // per-head QKV emitter: 5 N-tiles (80 cols: q24|k24|v24|pad8) over 4 waves
    auto qkv_head = [&](int hh, int qb) {
        #pragma unroll
        for (int jt = 0; jt < 5; ++jt) {
            if (((hh*5 + jt) & 3) != wave) continue;
            const int s   = jt*16 + l16;           // 0..79 within head
            const int row = hh*80 + s;
            bf16x8 bw[3];
            #pragma unroll
            for (int kk = 0; kk < 3; ++kk)
                bw[kk] = *(const bf16x8*)(wq2 + (size_t)row*96 + kk*32 + quad*8);
            const float bias = bq2[row];
            #pragma unroll
            for (int mt = 0; mt < 4; ++mt) {
                f32x4 acc = {};
                #pragma unroll
                for (int kk = 0; kk < 3; ++kk) acc = mfma16(af[mt][kk], bw[kk], acc);
                const int tb = mt*16 + quad*4;
                if (s < 24) {
                    #pragma unroll
                    for (int r = 0; r < 4; ++r)
                        sm[qb + (tb+r)*40 + s] = (bf16)(acc[r] + bias);
                } else if (s < 48) {
                    #pragma unroll
                    for (int r = 0; r < 4; ++r)
                        sm[qb + 2560 + (tb+r)*24 + (s-24)] = (bf16)(acc[r] + bias);
                } else if (s < 72) {
                    bf16x4 pv;
                    #pragma unroll
                    for (int r = 0; r < 4; ++r) pv[r] = (bf16)(acc[r] + bias);
                    *(bf16x4*)&sm[qb + 4096 + (s-48)*72 + tb] = pv;
                }
            }
        }
    };

    // prologue: head 0 into buffer 0
    qkv_head(0, B0_E);
    __syncthreads();

    for (int h = 0; h < NH_; ++h) {
        const int cb = (h & 1) ? B1_E : B0_E;   // current buffer
        const int nb = (h & 1) ? B0_E : B1_E;   // next buffer

        // ---- issue next head's QKV (hides weight-load latency under scores) ----
        if (h < NH_-1) qkv_head(h+1, nb);

        // ---- scores + softmax (wave owns queries qrow0..+15) ----
        bf16x8 aq = *(const bf16x8*)&sm[cb + (qrow0 + l16)*40 + quad*8];
        f32x4 accS[4];
        #pragma unroll
        for (int kt = 0; kt < 4; ++kt) {
            bf16x8 bk = *(const bf16x8*)&sm[cb + 2560 + (kt*16+l16)*24 + quad*8];
            f32x4 z = {};
            accS[kt] = mfma16(aq, bk, z);
        }
        float s_[4][4];
        #pragma unroll
        for (int kt = 0; kt < 4; ++kt)
            #pragma unroll
            for (int r = 0; r < 4; ++r)
                s_[kt][r] = accS[kt][r] + rpb[rix[kt][r] + h] + mb[kt][r];
        #pragma unroll
        for (int r = 0; r < 4; ++r) {
            float m = fmaxf(fmaxf(s_[0][r], s_[1][r]), fmaxf(s_[2][r], s_[3][r]));
            m = fmaxf(m, __shfl_xor(m,1)); m = fmaxf(m, __shfl_xor(m,2));
            m = fmaxf(m, __shfl_xor(m,4)); m = fmaxf(m, __shfl_xor(m,8));
            float su = 0.f;
            #pragma unroll
            for (int kt = 0; kt < 4; ++kt) { s_[kt][r] = __expf(s_[kt][r]-m); su += s_[kt][r]; }
            su += __shfl_xor(su,1); su += __shfl_xor(su,2);
            su += __shfl_xor(su,4); su += __shfl_xor(su,8);
            const float inv = 1.f/su;
            #pragma unroll
            for (int kt = 0; kt < 4; ++kt)
                sm[P_E + (qrow0 + quad*4 + r)*72 + kt*16 + l16] = (bf16)(s_[kt][r]*inv);
        }
        __syncthreads();   // P ready; next head's QKV stores also complete

        // ---- PV -> attn-out cols h*24..+23 of AXO ----
        bf16x8 ap0 = *(const bf16x8*)&sm[P_E + (qrow0+l16)*72 + quad*8];
        bf16x8 ap1 = *(const bf16x8*)&sm[P_E + (qrow0+l16)*72 + 32 + quad*8];
        #pragma unroll
        for (int nt2 = 0; nt2 < 2; ++nt2) {
            const int d = nt2*16 + l16;
            bf16x8 bv0 = *(const bf16x8*)&sm[cb + 4096 + d*72 + quad*8];
            bf16x8 bv1 = *(const bf16x8*)&sm[cb + 4096 + d*72 + 32 + quad*8];
            f32x4 acc = {};
            acc = mfma16(ap0, bv0, acc);
            acc = mfma16(ap1, bv1, acc);
            if (d < HD_) {
                #pragma unroll
                for (int r = 0; r < 4; ++r)
                    sm[AXO_E + (qrow0 + quad*4 + r)*104 + h*24 + d] = (bf16)acc[r];
            }
        }
        __syncthreads();   // protect P (next scores) and cb (overwritten at h+2)
    }

    // ---- proj (wave-local rows; reads AXO into regs, writes AXO) ----
    {
        bf16x8 ao[3];
        #pragma unroll
        for (int kk = 0; kk < 3; ++kk)
            ao[kk] = *(const bf16x8*)&sm[AXO_E + (qrow0 + l16)*104 + kk*32 + quad*8];
        for (int nt = 0; nt < 6; ++nt) {
            const int oc = nt*16 + l16;
            bf16x8 bw[3];
            #pragma unroll
            for (int kk = 0; kk < 3; ++kk)
                bw[kk] = *(const bf16x8*)(wproj + (size_t)oc*96 + kk*32 + quad*8);
            f32x4 acc = {};
            #pragma unroll
            for (int kk = 0; kk < 3; ++kk) acc = mfma16(ao[kk], bw[kk], acc);
            #pragma unroll
            for (int r = 0; r < 4; ++r)
                sm[AXO_E + (qrow0 + quad*4 + r)*104 + oc] = (bf16)acc[r];
        }
    }
    __syncthreads();

    // ---- h = x(regs) + proj-out + proj_b -> AXO (bf16 h); LN2 -> MY ----
    {
        float hv[24]; float mu = 0.f, ss = 0.f;
        #pragma unroll
        for (int k = 0; k < 3; ++k) {
            bf16x8 po = *(const bf16x8*)&sm[AXO_E + t*104 + qa*24 + k*8];
            bf16x8 h8;
            #pragma unroll
            for (int j = 0; j < 8; ++j) {
                float hf = (float)xreg[k][j] + (float)po[j] + proj_b[qa*24 + k*8 + j];
                h8[j] = (bf16)hf;
                float hb = (float)h8[j];      // LN2 sees bf16-rounded h (matches prior impl)
                hv[k*8+j] = hb;
                mu += hb; ss += hb*hb;
            }
            *(bf16x8*)&sm[AXO_E + t*104 + qa*24 + k*8] = h8;
        }
        mu += __shfl_xor(mu,1); mu += __shfl_xor(mu,2);
        ss += __shfl_xor(ss,1); ss += __shfl_xor(ss,2);
        mu *= (1.f/C_);
        float rstd = rsqrtf(ss*(1.f/C_) - mu*mu + EPS_);
        #pragma unroll
        for (int k = 0; k < 3; ++k) {
            bf16x8 o;
            #pragma unroll
            for (int j = 0; j < 8; ++j) {
                const int c = qa*24 + k*8 + j;
                o[j] = (bf16)((hv[k*8+j]-mu)*rstd*n2w[c] + n2b[c]);
            }
            *(bf16x8*)&sm[MYG_E + t*104 + qa*24 + k*8] = o;   // MY overlays dead attn scratch
        }
    }
    __syncthreads();

    // ---- MLP: af2 from MY ----
    bf16x8 af2[4][3];
    #pragma unroll
    for (int mt = 0; mt < 4; ++mt)
        #pragma unroll
        for (int kk = 0; kk < 3; ++kk)
            af2[mt][kk] = *(const bf16x8*)&sm[MYG_E + (mt*16+l16)*104 + kk*32 + quad*8];
    __syncthreads();   // MY dead; MG overlays

    f32x4 acc2[6];
    #pragma unroll
    for (int n = 0; n < 6; ++n) acc2[n] = (f32x4){};

    for (int ci = 0; ci < 3; ++ci) {
        #pragma unroll
        for (int rep = 0; rep < 2; ++rep) {
            const int ntl = wave + rep*4;
            const int ub  = ci*128 + ntl*16;
            bf16x8 bw[3];
            #pragma unroll
            for (int kk = 0; kk < 3; ++kk)
                bw[kk] = *(const bf16x8*)(wfc1 + (size_t)(ub + l16)*96 + kk*32 + quad*8);
            const f32x4 b4 = *(const f32x4*)&fc1b[ub + quad*4];
            #pragma unroll
            for (int mt = 0; mt < 4; ++mt) {
                f32x4 acc = {};
                #pragma unroll
                for (int kk = 0; kk < 3; ++kk) acc = mfma16(bw[kk], af2[mt][kk], acc);
                bf16x4 g4;
                #pragma unroll
                for (int r = 0; r < 4; ++r) {
                    // gelu(x) = x * sigmoid(1.5957691x + 0.0713548x^3)
                    float tv = acc[r] + b4[r];
                    float uu = tv*tv;
                    float w  = tv*fmaf(-0.0713548165f, uu, -1.5957691216f);
                    float e  = __expf(w);
                    g4[r] = (bf16)(tv*__builtin_amdgcn_rcpf(1.f + e));
                }
                *(bf16x4*)&sm[MYG_E + (mt*16 + l16)*136 + ntl*16 + quad*4] = g4;
            }
        }
        __syncthreads();
        bf16x8 ag[4];
        #pragma unroll
        for (int kq = 0; kq < 4; ++kq)
            ag[kq] = *(const bf16x8*)&sm[MYG_E + (wave*16+l16)*136 + kq*32 + quad*8];
        #pragma unroll
        for (int nt2 = 0; nt2 < 6; ++nt2) {
            const int c = nt2*16 + l16;
            #pragma unroll
            for (int kq = 0; kq < 4; ++kq) {
                bf16x8 bw = *(const bf16x8*)(wfc2 + (size_t)c*384 + ci*128 + kq*32 + quad*8);
                acc2[nt2] = mfma16(ag[kq], bw, acc2[nt2]);
            }
        }
        if (ci < 2) __syncthreads();
    }

    // ---- out = h + mlp (+fc2b); h from AXO; direct NCHW f32x4 store ----
    {
        const int row = wave*16 + quad*4;             // 4 consecutive window tokens, same row
        const int gh  = (wh*WS_ + (row>>3) + SHIFT_) & (H_-1);
        const int gw0 = (ww*WS_ + (row&7)  + SHIFT_) & (W_-1);   // 4-aligned
        #pragma unroll
        for (int nt2 = 0; nt2 < 6; ++nt2) {
            const int c = nt2*16 + l16;
            const float bias = fc2b[c];
            f32x4 o;
            #pragma unroll
            for (int r = 0; r < 4; ++r)
                o[r] = acc2[nt2][r] + bias + (float)sm[AXO_E + (row+r)*104 + c];
            *(f32x4*)(out + (size_t)(b*96 + c)*HW_ + gh*W_ + gw0) = o;
        }
    }
}

extern "C" void kernel_launch(void* const* d_in, const int* in_sizes, int n_in,
                              void* d_out, int out_size, void* d_ws, size_t ws_size,
                              hipStream_t stream) {
    const float* x      = (const float*)d_in[0];
    const float* norm_w = (const float*)d_in[1];
    const float* norm_b = (const float*)d_in[2];
    const float* qkv_w  = (const float*)d_in[3];
    const float* qkv_b  = (const float*)d_in[4];
    const float* proj_w = (const float*)d_in[5];
    const float* proj_b = (const float*)d_in[6];
    const float* rpb    = (const float*)d_in[7];
    const float* n2w    = (const float*)d_in[8];
    const float* n2b    = (const float*)d_in[9];
    const float* fc1w   = (const float*)d_in[10];
    const float* fc1b   = (const float*)d_in[11];
    const float* fc2w   = (const float*)d_in[12];
    const float* fc2b   = (const float*)d_in[13];

    float* outp = (float*)d_out;
    char*  ws   = (char*)d_ws;
    bf16*  wa   = (bf16*)ws;                         // weight arena
    float* bq2  = (float*)(ws + (size_t)WSUM_E*2);

    prepw_kernel<<<WBLKS, 256, 0, stream>>>(qkv_w, qkv_b, proj_w, fc1w, fc2w, wa, bq2);
    fused_kernel<<<B_*1024, 256, 0, stream>>>(x, norm_w, norm_b,
                                              wa, bq2,
                                              wa + WQ2_E, proj_b, rpb,
                                              n2w, n2b,
                                              wa + WQ2_E + WPR_E, fc1b,
                                              wa + WQ2_E + WPR_E + WF1_E, fc2b,
                                              outp);
}

// Round 10
// 515.670 us; speedup vs baseline: 1.0891x; 1.0891x over previous
//
#include <hip/hip_runtime.h>
#include <hip/hip_bf16.h>
#include <math.h>

// ---- problem constants ----
constexpr int B_    = 4;
constexpr int C_    = 96;
constexpr int H_    = 256;
constexpr int W_    = 256;
constexpr int WS_   = 8;
constexpr int NH_   = 4;
constexpr int SHIFT_= 4;
constexpr int HD_   = 24;
constexpr int HW_   = H_*W_;
constexpr float EPS_   = 1e-6f;
constexpr float SCALE_ = 0.20412414523193150f; // 24^-0.5

using bf16   = __bf16;
using bf16x8 = __attribute__((ext_vector_type(8))) __bf16;
using bf16x4 = __attribute__((ext_vector_type(4))) __bf16;
using f32x4  = __attribute__((ext_vector_type(4))) float;

__device__ __forceinline__ f32x4 mfma16(bf16x8 a, bf16x8 b, f32x4 c) {
    return __builtin_amdgcn_mfma_f32_16x16x32_bf16(a, b, c, 0, 0, 0);
}

// ---- weight arena (bf16 elements) ----
constexpr int    WQ2_E   = 320*96;                        // per-head q|k|v|pad
constexpr int    WPR_E   = 96*96;
constexpr int    WF1_E   = 384*96;
constexpr int    WF2_E   = 96*384;
constexpr int    WSUM_E  = WQ2_E + WPR_E + WF1_E + WF2_E; // 113664
constexpr int    NBQ     = 320;
constexpr int    WBLKS   = (WSUM_E + NBQ + 255)/256;      // 446

__global__ __launch_bounds__(256) void prepw_kernel(
    const float* __restrict__ qkv_w, const float* __restrict__ qkv_b,
    const float* __restrict__ proj_w, const float* __restrict__ fc1w,
    const float* __restrict__ fc2w,
    bf16* __restrict__ warena, float* __restrict__ bq2)
{
    int i = blockIdx.x*256 + threadIdx.x;
    if (i < WQ2_E) {
        int R = i/96, c = i%96;
        int h = R/80, s = R%80;
        float v;
        if      (s < 24) v = qkv_w[(h*24+s)*96 + c] * SCALE_;
        else if (s < 48) v = qkv_w[(96 + h*24 + s-24)*96 + c];
        else if (s < 72) v = qkv_w[(192 + h*24 + s-48)*96 + c];
        else             v = 0.f;
        warena[i] = (bf16)v;
    } else if (i < WQ2_E + WPR_E) {
        warena[i] = (bf16)proj_w[i - WQ2_E];
    } else if (i < WQ2_E + WPR_E + WF1_E) {
        warena[i] = (bf16)fc1w[i - WQ2_E - WPR_E];
    } else if (i < WSUM_E) {
        warena[i] = (bf16)fc2w[i - WQ2_E - WPR_E - WF1_E];
    } else if (i < WSUM_E + NBQ) {
        int j = i - WSUM_E;
        int h = j/80, s = j%80;
        float v;
        if      (s < 24) v = qkv_b[h*24+s] * SCALE_;
        else if (s < 48) v = qkv_b[96 + h*24 + s-24];
        else if (s < 72) v = qkv_b[192 + h*24 + s-48];
        else             v = 0.f;
        bq2[j] = v;
    }
}

// ---- fused kernel LDS layout (bf16 element offsets) ----
// AXO [64][104] : x-bf16 -> ln1 (in place) -> attn-out -> proj-out -> h
// B0/B1: double-buffered per-head QKV: Q[64][40] | K[64][24] | V^T[24][72]
//        (K b-frag tail spills into same buffer's V: junk x 0)
// P  [64][72] : softmax output (single buffer; reused across heads)
// MLP: MY [64][104] then MG [64][136] overlay B0 region (dead after attn).
constexpr int AXO_E = 0;
constexpr int B0_E  = 6656;
constexpr int B1_E  = 12480;            // B0_E + 5824
constexpr int P_E   = 18304;            // B1_E + 5824
constexpr int MYG_E = 6656;             // MLP overlay (B0/B1/P dead)
constexpr int SM_E  = 22912;            // el = 45824 B -> 3 blocks/CU

__global__ __launch_bounds__(256, 2) void fused_kernel(
    const float* __restrict__ x,       // [B,C,H,W] f32
    const float* __restrict__ norm_w, const float* __restrict__ norm_b,
    const bf16*  __restrict__ wq2,     // [320][96] per-head q|k|v|pad
    const float* __restrict__ bq2,     // [320]
    const bf16*  __restrict__ wproj,   // [96][96]
    const float* __restrict__ proj_b,
    const float* __restrict__ rpb,     // [225][4] f32
    const float* __restrict__ n2w, const float* __restrict__ n2b,
    const bf16*  __restrict__ wfc1, const float* __restrict__ fc1b,
    const bf16*  __restrict__ wfc2, const float* __restrict__ fc2b,
    float* __restrict__ out)           // [B,C,H,W] f32
{
    __shared__ __align__(16) bf16 sm[SM_E];

    const int tid  = threadIdx.x;
    const int wave = tid >> 6, lane = tid & 63;
    const int l16  = lane & 15, quad = lane >> 4;
    const int t  = tid >> 2, qa = tid & 3;
    const int qrow0 = wave*16;

    const int blk = blockIdx.x;
    const int b   = blk >> 10;
    const int wid = blk & 1023;
    const int wh  = wid >> 5, ww = wid & 31;

    // ---- Phase A: gather window's x (f32 NCHW, shifted+wrapped) -> AXO bf16 ----
    #pragma unroll
    for (int it = 0; it < 6; ++it) {
        const int i2  = it*256 + tid;          // 0..1535
        const int c   = i2 >> 4;               // 0..95
        const int rem = i2 & 15;
        const int wi  = rem >> 1;
        const int wj4 = (rem & 1)*4;
        const int gh  = (wh*WS_ + wi + SHIFT_) & (H_-1);
        const int gw0 = (ww*WS_ + wj4 + SHIFT_) & (W_-1);  // 4-aligned, no 16B crossing
        f32x4 v4 = *(const f32x4*)(x + (size_t)(b*96 + c)*HW_ + gh*W_ + gw0);
        #pragma unroll
        for (int j = 0; j < 4; ++j)
            sm[AXO_E + (wi*8 + wj4 + j)*104 + c] = (bf16)v4[j];
    }
    __syncthreads();

    // ---- Phase B0: LN1 in place (thread-local rows); x kept in REGISTERS ----
    bf16x8 xreg[3];                    // this thread's 24 x channels (residual)
    {
        float v[24]; float mu = 0.f, ss = 0.f;
        #pragma unroll
        for (int k = 0; k < 3; ++k) {
            xreg[k] = *(const bf16x8*)&sm[AXO_E + t*104 + qa*24 + k*8];
            #pragma unroll
            for (int j = 0; j < 8; ++j) {
                v[k*8+j] = (float)xreg[k][j];
                mu += v[k*8+j]; ss += v[k*8+j]*v[k*8+j];
            }
        }
        mu += __shfl_xor(mu,1); mu += __shfl_xor(mu,2);
        ss += __shfl_xor(ss,1); ss += __shfl_xor(ss,2);
        mu *= (1.f/C_);
        float rstd = rsqrtf(ss*(1.f/C_) - mu*mu + EPS_);
        #pragma unroll
        for (int k = 0; k < 3; ++k) {
            bf16x8 ln8;
            #pragma unroll
            for (int j = 0; j < 8; ++j) {
                const int c = qa*24 + k*8 + j;
                ln8[j] = (bf16)((v[k*8+j]-mu)*rstd*norm_w[c] + norm_b[c]);
            }
            *(bf16x8*)&sm[AXO_E + t*104 + qa*24 + k*8] = ln8;
        }
    }
    __syncthreads();   // AXO now holds xln

    // zero Q pad cols 24..31 of BOTH buffers (QKV stores never touch them)
    if (tid < 128) {
        bf16x8 z = {};
        const int bb = (tid >> 6) ? B1_E : B0_E;
        *(bf16x8*)&sm[bb + (tid & 63)*40 + 24] = z;
    }

    // A-frags of LN'd x, kept in registers for all heads
    bf16x8 af[4][3];
    #pragma unroll
    for (int mt = 0; mt < 4; ++mt)
        #pragma unroll
        for (int kk = 0; kk < 3; ++kk)
            af[mt][kk] = *(const bf16x8*)&sm[AXO_E + (mt*16+l16)*104 + kk*32 + quad*8];

    // ---- hoisted mask/bias index precompute (head-invariant) ----
    int   rix[4][4];   // rpb row index * NH_
    float mb [4][4];   // 0 or -100 shift mask term
    #pragma unroll
    for (int kt = 0; kt < 4; ++kt) {
        const int key = kt*16 + l16;
        const int ki = key >> 3, kj = key & 7;
        const int labk = (((wh*8+ki) >= H_-WS_) + ((wh*8+ki) >= H_-SHIFT_))*3
                       +  ((ww*8+kj) >= W_-WS_) + ((ww*8+kj) >= W_-SHIFT_);
        #pragma unroll
        for (int r = 0; r < 4; ++r) {
            const int q = qrow0 + quad*4 + r;
            const int ti = q >> 3, tj = q & 7;
            const int labq = (((wh*8+ti) >= H_-WS_) + ((wh*8+ti) >= H_-SHIFT_))*3
                           +  ((ww*8+tj) >= W_-WS_) + ((ww*8+tj) >= W_-SHIFT_);
            rix[kt][r] = ((ti - ki + 7)*15 + (tj - kj + 7))*NH_;
            mb [kt][r] = (labk != labq) ? -100.f : 0.f;
        }
    }

    // per-head QKV emitter: 5 N-tiles (80 cols: q24|k24|v24|pad8) over 4 waves
    auto qkv_head = [&](int hh, int qb) {
        #pragma unroll
        for (int jt = 0; jt < 5; ++jt) {
            if (((hh*5 + jt) & 3) != wave) continue;
            const int s   = jt*16 + l16;           // 0..79 within head
            const int row = hh*80 + s;
            bf16x8 bw[3];
            #pragma unroll
            for (int kk = 0; kk < 3; ++kk)
                bw[kk] = *(const bf16x8*)(wq2 + (size_t)row*96 + kk*32 + quad*8);
            const float bias = bq2[row];
            #pragma unroll
            for (int mt = 0; mt < 4; ++mt) {
                f32x4 acc = {};
                #pragma unroll
                for (int kk = 0; kk < 3; ++kk) acc = mfma16(af[mt][kk], bw[kk], acc);
                const int tb = mt*16 + quad*4;
                if (s < 24) {
                    #pragma unroll
                    for (int r = 0; r < 4; ++r)
                        sm[qb + (tb+r)*40 + s] = (bf16)(acc[r] + bias);
                } else if (s < 48) {
                    #pragma unroll
                    for (int r = 0; r < 4; ++r)
                        sm[qb + 2560 + (tb+r)*24 + (s-24)] = (bf16)(acc[r] + bias);
                } else if (s < 72) {
                    bf16x4 pv;
                    #pragma unroll
                    for (int r = 0; r < 4; ++r) pv[r] = (bf16)(acc[r] + bias);
                    *(bf16x4*)&sm[qb + 4096 + (s-48)*72 + tb] = pv;
                }
            }
        }
    };

    // prologue: head 0 into buffer 0
    qkv_head(0, B0_E);
    __syncthreads();

    for (int h = 0; h < NH_; ++h) {
        const int cb = (h & 1) ? B1_E : B0_E;   // current buffer
        const int nb = (h & 1) ? B0_E : B1_E;   // next buffer

        // ---- issue next head's QKV (hides weight-load latency under scores) ----
        if (h < NH_-1) qkv_head(h+1, nb);

        // ---- scores + softmax (wave owns queries qrow0..+15) ----
        bf16x8 aq = *(const bf16x8*)&sm[cb + (qrow0 + l16)*40 + quad*8];
        f32x4 accS[4];
        #pragma unroll
        for (int kt = 0; kt < 4; ++kt) {
            bf16x8 bk = *(const bf16x8*)&sm[cb + 2560 + (kt*16+l16)*24 + quad*8];
            f32x4 z = {};
            accS[kt] = mfma16(aq, bk, z);
        }
        float s_[4][4];
        #pragma unroll
        for (int kt = 0; kt < 4; ++kt)
            #pragma unroll
            for (int r = 0; r < 4; ++r)
                s_[kt][r] = accS[kt][r] + rpb[rix[kt][r] + h] + mb[kt][r];
        #pragma unroll
        for (int r = 0; r < 4; ++r) {
            float m = fmaxf(fmaxf(s_[0][r], s_[1][r]), fmaxf(s_[2][r], s_[3][r]));
            m = fmaxf(m, __shfl_xor(m,1)); m = fmaxf(m, __shfl_xor(m,2));
            m = fmaxf(m, __shfl_xor(m,4)); m = fmaxf(m, __shfl_xor(m,8));
            float su = 0.f;
            #pragma unroll
            for (int kt = 0; kt < 4; ++kt) { s_[kt][r] = __expf(s_[kt][r]-m); su += s_[kt][r]; }
            su += __shfl_xor(su,1); su += __shfl_xor(su,2);
            su += __shfl_xor(su,4); su += __shfl_xor(su,8);
            const float inv = 1.f/su;
            #pragma unroll
            for (int kt = 0; kt < 4; ++kt)
                sm[P_E + (qrow0 + quad*4 + r)*72 + kt*16 + l16] = (bf16)(s_[kt][r]*inv);
        }
        __syncthreads();   // P ready; next head's QKV stores also complete

        // ---- PV -> attn-out cols h*24..+23 of AXO ----
        bf16x8 ap0 = *(const bf16x8*)&sm[P_E + (qrow0+l16)*72 + quad*8];
        bf16x8 ap1 = *(const bf16x8*)&sm[P_E + (qrow0+l16)*72 + 32 + quad*8];
        #pragma unroll
        for (int nt2 = 0; nt2 < 2; ++nt2) {
            const int d = nt2*16 + l16;
            bf16x8 bv0 = *(const bf16x8*)&sm[cb + 4096 + d*72 + quad*8];
            bf16x8 bv1 = *(const bf16x8*)&sm[cb + 4096 + d*72 + 32 + quad*8];
            f32x4 acc = {};
            acc = mfma16(ap0, bv0, acc);
            acc = mfma16(ap1, bv1, acc);
            if (d < HD_) {
                #pragma unroll
                for (int r = 0; r < 4; ++r)
                    sm[AXO_E + (qrow0 + quad*4 + r)*104 + h*24 + d] = (bf16)acc[r];
            }
        }
        __syncthreads();   // protect P (next scores) and cb (overwritten at h+2)
    }

    // ---- proj (wave-local rows; reads AXO into regs, writes AXO) ----
    {
        bf16x8 ao[3];
        #pragma unroll
        for (int kk = 0; kk < 3; ++kk)
            ao[kk] = *(const bf16x8*)&sm[AXO_E + (qrow0 + l16)*104 + kk*32 + quad*8];
        for (int nt = 0; nt < 6; ++nt) {
            const int oc = nt*16 + l16;
            bf16x8 bw[3];
            #pragma unroll
            for (int kk = 0; kk < 3; ++kk)
                bw[kk] = *(const bf16x8*)(wproj + (size_t)oc*96 + kk*32 + quad*8);
            f32x4 acc = {};
            #pragma unroll
            for (int kk = 0; kk < 3; ++kk) acc = mfma16(ao[kk], bw[kk], acc);
            #pragma unroll
            for (int r = 0; r < 4; ++r)
                sm[AXO_E + (qrow0 + quad*4 + r)*104 + oc] = (bf16)acc[r];
        }
    }
    __syncthreads();

    // ---- h = x(regs) + proj-out + proj_b -> AXO (bf16 h); LN2 -> MY ----
    {
        float hv[24]; float mu = 0.f, ss = 0.f;
        #pragma unroll
        for (int k = 0; k < 3; ++k) {
            bf16x8 po = *(const bf16x8*)&sm[AXO_E + t*104 + qa*24 + k*8];
            bf16x8 h8;
            #pragma unroll
            for (int j = 0; j < 8; ++j) {
                float hf = (float)xreg[k][j] + (float)po[j] + proj_b[qa*24 + k*8 + j];
                h8[j] = (bf16)hf;
                float hb = (float)h8[j];      // LN2 sees bf16-rounded h (matches prior impl)
                hv[k*8+j] = hb;
                mu += hb; ss += hb*hb;
            }
            *(bf16x8*)&sm[AXO_E + t*104 + qa*24 + k*8] = h8;
        }
        mu += __shfl_xor(mu,1); mu += __shfl_xor(mu,2);
        ss += __shfl_xor(ss,1); ss += __shfl_xor(ss,2);
        mu *= (1.f/C_);
        float rstd = rsqrtf(ss*(1.f/C_) - mu*mu + EPS_);
        #pragma unroll
        for (int k = 0; k < 3; ++k) {
            bf16x8 o;
            #pragma unroll
            for (int j = 0; j < 8; ++j) {
                const int c = qa*24 + k*8 + j;
                o[j] = (bf16)((hv[k*8+j]-mu)*rstd*n2w[c] + n2b[c]);
            }
            *(bf16x8*)&sm[MYG_E + t*104 + qa*24 + k*8] = o;   // MY overlays dead attn scratch
        }
    }
    __syncthreads();

    // ---- MLP: af2 from MY ----
    bf16x8 af2[4][3];
    #pragma unroll
    for (int mt = 0; mt < 4; ++mt)
        #pragma unroll
        for (int kk = 0; kk < 3; ++kk)
            af2[mt][kk] = *(const bf16x8*)&sm[MYG_E + (mt*16+l16)*104 + kk*32 + quad*8];
    __syncthreads();   // MY dead; MG overlays

    f32x4 acc2[6];
    #pragma unroll
    for (int n = 0; n < 6; ++n) acc2[n] = (f32x4){};

    for (int ci = 0; ci < 3; ++ci) {
        #pragma unroll
        for (int rep = 0; rep < 2; ++rep) {
            const int ntl = wave + rep*4;
            const int ub  = ci*128 + ntl*16;
            bf16x8 bw[3];
            #pragma unroll
            for (int kk = 0; kk < 3; ++kk)
                bw[kk] = *(const bf16x8*)(wfc1 + (size_t)(ub + l16)*96 + kk*32 + quad*8);
            const f32x4 b4 = *(const f32x4*)&fc1b[ub + quad*4];
            #pragma unroll
            for (int mt = 0; mt < 4; ++mt) {
                f32x4 acc = {};
                #pragma unroll
                for (int kk = 0; kk < 3; ++kk) acc = mfma16(bw[kk], af2[mt][kk], acc);
                bf16x4 g4;
                #pragma unroll
                for (int r = 0; r < 4; ++r) {
                    // gelu(x) = x * sigmoid(1.5957691x + 0.0713548x^3)
                    float tv = acc[r] + b4[r];
                    float uu = tv*tv;
                    float w  = tv*fmaf(-0.0713548165f, uu, -1.5957691216f);
                    float e  = __expf(w);
                    g4[r] = (bf16)(tv*__builtin_amdgcn_rcpf(1.f + e));
                }
                *(bf16x4*)&sm[MYG_E + (mt*16 + l16)*136 + ntl*16 + quad*4] = g4;
            }
        }
        __syncthreads();
        bf16x8 ag[4];
        #pragma unroll
        for (int kq = 0; kq < 4; ++kq)
            ag[kq] = *(const bf16x8*)&sm[MYG_E + (wave*16+l16)*136 + kq*32 + quad*8];
        #pragma unroll
        for (int nt2 = 0; nt2 < 6; ++nt2) {
            const int c = nt2*16 + l16;
            #pragma unroll
            for (int kq = 0; kq < 4; ++kq) {
                bf16x8 bw = *(const bf16x8*)(wfc2 + (size_t)c*384 + ci*128 + kq*32 + quad*8);
                acc2[nt2] = mfma16(ag[kq], bw, acc2[nt2]);
            }
        }
        if (ci < 2) __syncthreads();
    }

    // ---- out = h + mlp (+fc2b); h from AXO; direct NCHW f32x4 store ----
    {
        const int row = wave*16 + quad*4;             // 4 consecutive window tokens, same row
        const int gh  = (wh*WS_ + (row>>3) + SHIFT_) & (H_-1);
        const int gw0 = (ww*WS_ + (row&7)  + SHIFT_) & (W_-1);   // 4-aligned
        #pragma unroll
        for (int nt2 = 0; nt2 < 6; ++nt2) {
            const int c = nt2*16 + l16;
            const float bias = fc2b[c];
            f32x4 o;
            #pragma unroll
            for (int r = 0; r < 4; ++r)
                o[r] = acc2[nt2][r] + bias + (float)sm[AXO_E + (row+r)*104 + c];
            *(f32x4*)(out + (size_t)(b*96 + c)*HW_ + gh*W_ + gw0) = o;
        }
    }
}

extern "C" void kernel_launch(void* const* d_in, const int* in_sizes, int n_in,
                              void* d_out, int out_size, void* d_ws, size_t ws_size,
                              hipStream_t stream) {
    const float* x      = (const float*)d_in[0];
    const float* norm_w = (const float*)d_in[1];
    const float* norm_b = (const float*)d_in[2];
    const float* qkv_w  = (const float*)d_in[3];
    const float* qkv_b  = (const float*)d_in[4];
    const float* proj_w = (const float*)d_in[5];
    const float* proj_b = (const float*)d_in[6];
    const float* rpb    = (const float*)d_in[7];
    const float* n2w    = (const float*)d_in[8];
    const float* n2b    = (const float*)d_in[9];
    const float* fc1w   = (const float*)d_in[10];
    const float* fc1b   = (const float*)d_in[11];
    const float* fc2w   = (const float*)d_in[12];
    const float* fc2b   = (const float*)d_in[13];

    float* outp = (float*)d_out;
    char*  ws   = (char*)d_ws;
    bf16*  wa   = (bf16*)ws;                         // weight arena
    float* bq2  = (float*)(ws + (size_t)WSUM_E*2);

    prepw_kernel<<<WBLKS, 256, 0, stream>>>(qkv_w, qkv_b, proj_w, fc1w, fc2w, wa, bq2);
    fused_kernel<<<B_*1024, 256, 0, stream>>>(x, norm_w, norm_b,
                                              wa, bq2,
                                              wa + WQ2_E, proj_b, rpb,
                                              n2w, n2b,
                                              wa + WQ2_E + WPR_E, fc1b,
                                              wa + WQ2_E + WPR_E + WF1_E, fc2b,
                                              outp);
}

// Round 11
// 484.195 us; speedup vs baseline: 1.1598x; 1.0650x over previous
//
#include <hip/hip_runtime.h>
#include <hip/hip_bf16.h>
#include <math.h>

// ---- problem constants ----
constexpr int B_    = 4;
constexpr int C_    = 96;
constexpr int H_    = 256;
constexpr int W_    = 256;
constexpr int WS_   = 8;
constexpr int NH_   = 4;
constexpr int SHIFT_= 4;
constexpr int HD_   = 24;
constexpr int HW_   = H_*W_;
constexpr float EPS_   = 1e-6f;
constexpr float SCALE_ = 0.20412414523193150f; // 24^-0.5

using bf16   = __bf16;
using bf16x8 = __attribute__((ext_vector_type(8))) __bf16;
using bf16x4 = __attribute__((ext_vector_type(4))) __bf16;
using f32x4  = __attribute__((ext_vector_type(4))) float;

__device__ __forceinline__ f32x4 mfma16(bf16x8 a, bf16x8 b, f32x4 c) {
    return __builtin_amdgcn_mfma_f32_16x16x32_bf16(a, b, c, 0, 0, 0);
}

// ---- weight arena (bf16 elements) ----
constexpr int    WQ2_E   = 320*96;                        // per-head q|k|v|pad
constexpr int    WPR_E   = 96*96;
constexpr int    WF1_E   = 384*96;
constexpr int    WF2_E   = 96*384;
constexpr int    WSUM_E  = WQ2_E + WPR_E + WF1_E + WF2_E; // 113664
constexpr int    NBQ     = 320;
constexpr int    WBLKS   = (WSUM_E + NBQ + 255)/256;      // 446

__global__ __launch_bounds__(256) void prepw_kernel(
    const float* __restrict__ qkv_w, const float* __restrict__ qkv_b,
    const float* __restrict__ proj_w, const float* __restrict__ fc1w,
    const float* __restrict__ fc2w,
    bf16* __restrict__ warena, float* __restrict__ bq2)
{
    int i = blockIdx.x*256 + threadIdx.x;
    if (i < WQ2_E) {
        int R = i/96, c = i%96;
        int h = R/80, s = R%80;
        float v;
        if      (s < 24) v = qkv_w[(h*24+s)*96 + c] * SCALE_;
        else if (s < 48) v = qkv_w[(96 + h*24 + s-24)*96 + c];
        else if (s < 72) v = qkv_w[(192 + h*24 + s-48)*96 + c];
        else             v = 0.f;
        warena[i] = (bf16)v;
    } else if (i < WQ2_E + WPR_E) {
        warena[i] = (bf16)proj_w[i - WQ2_E];
    } else if (i < WQ2_E + WPR_E + WF1_E) {
        warena[i] = (bf16)fc1w[i - WQ2_E - WPR_E];
    } else if (i < WSUM_E) {
        warena[i] = (bf16)fc2w[i - WQ2_E - WPR_E - WF1_E];
    } else if (i < WSUM_E + NBQ) {
        int j = i - WSUM_E;
        int h = j/80, s = j%80;
        float v;
        if      (s < 24) v = qkv_b[h*24+s] * SCALE_;
        else if (s < 48) v = qkv_b[96 + h*24 + s-24];
        else if (s < 72) v = qkv_b[192 + h*24 + s-48];
        else             v = 0.f;
        bq2[j] = v;
    }
}

// ---- fused kernel LDS layout (bf16 element offsets) ----
// AXO [64][104] : x-bf16 -> ln1 (in place) -> attn-out -> proj-out -> h
// B0/B1: double-buffered per-head QKV: Q[64][40] | K[64][24] | V^T[24][72]
//        (K b-frag tail spills into same buffer's V: junk x 0)
// P  [64][72] : softmax output (single buffer; reused across heads)
// MLP: MY [64][104] then MG [64][136] overlay B0 region (dead after attn).
constexpr int AXO_E = 0;
constexpr int B0_E  = 6656;
constexpr int B1_E  = 12480;            // B0_E + 5824
constexpr int P_E   = 18304;            // B1_E + 5824
constexpr int MYG_E = 6656;             // MLP overlay (B0/B1/P dead)
constexpr int SM_E  = 22912;            // el = 45824 B -> 3 blocks/CU

__global__ __launch_bounds__(256, 2) void fused_kernel(
    const float* __restrict__ x,       // [B,C,H,W] f32
    const float* __restrict__ norm_w, const float* __restrict__ norm_b,
    const bf16*  __restrict__ wq2,     // [320][96] per-head q|k|v|pad
    const float* __restrict__ bq2,     // [320]
    const bf16*  __restrict__ wproj,   // [96][96]
    const float* __restrict__ proj_b,
    const float* __restrict__ rpb,     // [225][4] f32
    const float* __restrict__ n2w, const float* __restrict__ n2b,
    const bf16*  __restrict__ wfc1, const float* __restrict__ fc1b,
    const bf16*  __restrict__ wfc2, const float* __restrict__ fc2b,
    float* __restrict__ out)           // [B,C,H,W] f32
{
    __shared__ __align__(16) bf16 sm[SM_E];

    const int tid  = threadIdx.x;
    const int wave = tid >> 6, lane = tid & 63;
    const int l16  = lane & 15, quad = lane >> 4;
    const int t  = tid >> 2, qa = tid & 3;
    const int qrow0 = wave*16;

    // XCD-chunked bijective swizzle (4096 % 8 == 0): each XCD owns a contiguous
    // 512-window chunk, so horizontally adjacent windows (which share 64B lines
    // of x/out) land on the SAME XCD's L2 -> partial-line reads/writes merge.
    const int blk = (blockIdx.x & 7)*512 + (blockIdx.x >> 3);
    const int b   = blk >> 10;
    const int wid = blk & 1023;
    const int wh  = wid >> 5, ww = wid & 31;

    // ---- Phase A: gather window's x (f32 NCHW, shifted+wrapped) -> AXO bf16 ----
    #pragma unroll
    for (int it = 0; it < 6; ++it) {
        const int i2  = it*256 + tid;          // 0..1535
        const int c   = i2 >> 4;               // 0..95
        const int rem = i2 & 15;
        const int wi  = rem >> 1;
        const int wj4 = (rem & 1)*4;
        const int gh  = (wh*WS_ + wi + SHIFT_) & (H_-1);
        const int gw0 = (ww*WS_ + wj4 + SHIFT_) & (W_-1);  // 4-aligned, no 16B crossing
        f32x4 v4 = *(const f32x4*)(x + (size_t)(b*96 + c)*HW_ + gh*W_ + gw0);
        #pragma unroll
        for (int j = 0; j < 4; ++j)
            sm[AXO_E + (wi*8 + wj4 + j)*104 + c] = (bf16)v4[j];
    }
    __syncthreads();

    // ---- Phase B0: LN1 in place (thread-local rows); x kept in REGISTERS ----
    bf16x8 xreg[3];                    // this thread's 24 x channels (residual)
    {
        float v[24]; float mu = 0.f, ss = 0.f;
        #pragma unroll
        for (int k = 0; k < 3; ++k) {
            xreg[k] = *(const bf16x8*)&sm[AXO_E + t*104 + qa*24 + k*8];
            #pragma unroll
            for (int j = 0; j < 8; ++j) {
                v[k*8+j] = (float)xreg[k][j];
                mu += v[k*8+j]; ss += v[k*8+j]*v[k*8+j];
            }
        }
        mu += __shfl_xor(mu,1); mu += __shfl_xor(mu,2);
        ss += __shfl_xor(ss,1); ss += __shfl_xor(ss,2);
        mu *= (1.f/C_);
        float rstd = rsqrtf(ss*(1.f/C_) - mu*mu + EPS_);
        #pragma unroll
        for (int k = 0; k < 3; ++k) {
            bf16x8 ln8;
            #pragma unroll
            for (int j = 0; j < 8; ++j) {
                const int c = qa*24 + k*8 + j;
                ln8[j] = (bf16)((v[k*8+j]-mu)*rstd*norm_w[c] + norm_b[c]);
            }
            *(bf16x8*)&sm[AXO_E + t*104 + qa*24 + k*8] = ln8;
        }
    }
    __syncthreads();   // AXO now holds xln

    // zero Q pad cols 24..31 of BOTH buffers (QKV stores never touch them)
    if (tid < 128) {
        bf16x8 z = {};
        const int bb = (tid >> 6) ? B1_E : B0_E;
        *(bf16x8*)&sm[bb + (tid & 63)*40 + 24] = z;
    }

    // A-frags of LN'd x, kept in registers for all heads
    bf16x8 af[4][3];
    #pragma unroll
    for (int mt = 0; mt < 4; ++mt)
        #pragma unroll
        for (int kk = 0; kk < 3; ++kk)
            af[mt][kk] = *(const bf16x8*)&sm[AXO_E + (mt*16+l16)*104 + kk*32 + quad*8];

    // ---- hoisted mask/bias index precompute (head-invariant) ----
    int   rix[4][4];   // rpb row index * NH_
    float mb [4][4];   // 0 or -100 shift mask term
    #pragma unroll
    for (int kt = 0; kt < 4; ++kt) {
        const int key = kt*16 + l16;
        const int ki = key >> 3, kj = key & 7;
        const int labk = (((wh*8+ki) >= H_-WS_) + ((wh*8+ki) >= H_-SHIFT_))*3
                       +  ((ww*8+kj) >= W_-WS_) + ((ww*8+kj) >= W_-SHIFT_);
        #pragma unroll
        for (int r = 0; r < 4; ++r) {
            const int q = qrow0 + quad*4 + r;
            const int ti = q >> 3, tj = q & 7;
            const int labq = (((wh*8+ti) >= H_-WS_) + ((wh*8+ti) >= H_-SHIFT_))*3
                           +  ((ww*8+tj) >= W_-WS_) + ((ww*8+tj) >= W_-SHIFT_);
            rix[kt][r] = ((ti - ki + 7)*15 + (tj - kj + 7))*NH_;
            mb [kt][r] = (labk != labq) ? -100.f : 0.f;
        }
    }

    // per-head QKV emitter: 5 N-tiles (80 cols: q24|k24|v24|pad8) over 4 waves
    auto qkv_head = [&](int hh, int qb) {
        #pragma unroll
        for (int jt = 0; jt < 5; ++jt) {
            if (((hh*5 + jt) & 3) != wave) continue;
            const int s   = jt*16 + l16;           // 0..79 within head
            const int row = hh*80 + s;
            bf16x8 bw[3];
            #pragma unroll
            for (int kk = 0; kk < 3; ++kk)
                bw[kk] = *(const bf16x8*)(wq2 + (size_t)row*96 + kk*32 + quad*8);
            const float bias = bq2[row];
            #pragma unroll
            for (int mt = 0; mt < 4; ++mt) {
                f32x4 acc = {};
                #pragma unroll
                for (int kk = 0; kk < 3; ++kk) acc = mfma16(af[mt][kk], bw[kk], acc);
                const int tb = mt*16 + quad*4;
                if (s < 24) {
                    #pragma unroll
                    for (int r = 0; r < 4; ++r)
                        sm[qb + (tb+r)*40 + s] = (bf16)(acc[r] + bias);
                } else if (s < 48) {
                    #pragma unroll
                    for (int r = 0; r < 4; ++r)
                        sm[qb + 2560 + (tb+r)*24 + (s-24)] = (bf16)(acc[r] + bias);
                } else if (s < 72) {
                    bf16x4 pv;
                    #pragma unroll
                    for (int r = 0; r < 4; ++r) pv[r] = (bf16)(acc[r] + bias);
                    *(bf16x4*)&sm[qb + 4096 + (s-48)*72 + tb] = pv;
                }
            }
        }
    };

    // prologue: head 0 into buffer 0
    qkv_head(0, B0_E);
    __syncthreads();

    for (int h = 0; h < NH_; ++h) {
        const int cb = (h & 1) ? B1_E : B0_E;   // current buffer
        const int nb = (h & 1) ? B0_E : B1_E;   // next buffer

        // ---- issue next head's QKV (hides weight-load latency under scores) ----
        if (h < NH_-1) qkv_head(h+1, nb);

        // ---- scores + softmax (wave owns queries qrow0..+15) ----
        bf16x8 aq = *(const bf16x8*)&sm[cb + (qrow0 + l16)*40 + quad*8];
        f32x4 accS[4];
        #pragma unroll
        for (int kt = 0; kt < 4; ++kt) {
            bf16x8 bk = *(const bf16x8*)&sm[cb + 2560 + (kt*16+l16)*24 + quad*8];
            f32x4 z = {};
            accS[kt] = mfma16(aq, bk, z);
        }
        float s_[4][4];
        #pragma unroll
        for (int kt = 0; kt < 4; ++kt)
            #pragma unroll
            for (int r = 0; r < 4; ++r)
                s_[kt][r] = accS[kt][r] + rpb[rix[kt][r] + h] + mb[kt][r];
        #pragma unroll
        for (int r = 0; r < 4; ++r) {
            float m = fmaxf(fmaxf(s_[0][r], s_[1][r]), fmaxf(s_[2][r], s_[3][r]));
            m = fmaxf(m, __shfl_xor(m,1)); m = fmaxf(m, __shfl_xor(m,2));
            m = fmaxf(m, __shfl_xor(m,4)); m = fmaxf(m, __shfl_xor(m,8));
            float su = 0.f;
            #pragma unroll
            for (int kt = 0; kt < 4; ++kt) { s_[kt][r] = __expf(s_[kt][r]-m); su += s_[kt][r]; }
            su += __shfl_xor(su,1); su += __shfl_xor(su,2);
            su += __shfl_xor(su,4); su += __shfl_xor(su,8);
            const float inv = 1.f/su;
            #pragma unroll
            for (int kt = 0; kt < 4; ++kt)
                sm[P_E + (qrow0 + quad*4 + r)*72 + kt*16 + l16] = (bf16)(s_[kt][r]*inv);
        }
        __syncthreads();   // P ready; next head's QKV stores also complete

        // ---- PV -> attn-out cols h*24..+23 of AXO ----
        bf16x8 ap0 = *(const bf16x8*)&sm[P_E + (qrow0+l16)*72 + quad*8];
        bf16x8 ap1 = *(const bf16x8*)&sm[P_E + (qrow0+l16)*72 + 32 + quad*8];
        #pragma unroll
        for (int nt2 = 0; nt2 < 2; ++nt2) {
            const int d = nt2*16 + l16;
            bf16x8 bv0 = *(const bf16x8*)&sm[cb + 4096 + d*72 + quad*8];
            bf16x8 bv1 = *(const bf16x8*)&sm[cb + 4096 + d*72 + 32 + quad*8];
            f32x4 acc = {};
            acc = mfma16(ap0, bv0, acc);
            acc = mfma16(ap1, bv1, acc);
            if (d < HD_) {
                #pragma unroll
                for (int r = 0; r < 4; ++r)
                    sm[AXO_E + (qrow0 + quad*4 + r)*104 + h*24 + d] = (bf16)acc[r];
            }
        }
        __syncthreads();   // protect P (next scores) and cb (overwritten at h+2)
    }

    // ---- proj (wave-local rows; reads AXO into regs, writes AXO) ----
    {
        bf16x8 ao[3];
        #pragma unroll
        for (int kk = 0; kk < 3; ++kk)
            ao[kk] = *(const bf16x8*)&sm[AXO_E + (qrow0 + l16)*104 + kk*32 + quad*8];
        for (int nt = 0; nt < 6; ++nt) {
            const int oc = nt*16 + l16;
            bf16x8 bw[3];
            #pragma unroll
            for (int kk = 0; kk < 3; ++kk)
                bw[kk] = *(const bf16x8*)(wproj + (size_t)oc*96 + kk*32 + quad*8);
            f32x4 acc = {};
            #pragma unroll
            for (int kk = 0; kk < 3; ++kk) acc = mfma16(ao[kk], bw[kk], acc);
            #pragma unroll
            for (int r = 0; r < 4; ++r)
                sm[AXO_E + (qrow0 + quad*4 + r)*104 + oc] = (bf16)acc[r];
        }
    }
    __syncthreads();

    // ---- h = x(regs) + proj-out + proj_b -> AXO (bf16 h); LN2 -> MY ----
    {
        float hv[24]; float mu = 0.f, ss = 0.f;
        #pragma unroll
        for (int k = 0; k < 3; ++k) {
            bf16x8 po = *(const bf16x8*)&sm[AXO_E + t*104 + qa*24 + k*8];
            bf16x8 h8;
            #pragma unroll
            for (int j = 0; j < 8; ++j) {
                float hf = (float)xreg[k][j] + (float)po[j] + proj_b[qa*24 + k*8 + j];
                h8[j] = (bf16)hf;
                float hb = (float)h8[j];      // LN2 sees bf16-rounded h (matches prior impl)
                hv[k*8+j] = hb;
                mu += hb; ss += hb*hb;
            }
            *(bf16x8*)&sm[AXO_E + t*104 + qa*24 + k*8] = h8;
        }
        mu += __shfl_xor(mu,1); mu += __shfl_xor(mu,2);
        ss += __shfl_xor(ss,1); ss += __shfl_xor(ss,2);
        mu *= (1.f/C_);
        float rstd = rsqrtf(ss*(1.f/C_) - mu*mu + EPS_);
        #pragma unroll
        for (int k = 0; k < 3; ++k) {
            bf16x8 o;
            #pragma unroll
            for (int j = 0; j < 8; ++j) {
                const int c = qa*24 + k*8 + j;
                o[j] = (bf16)((hv[k*8+j]-mu)*rstd*n2w[c] + n2b[c]);
            }
            *(bf16x8*)&sm[MYG_E + t*104 + qa*24 + k*8] = o;   // MY overlays dead attn scratch
        }
    }
    __syncthreads();

    // ---- MLP: af2 from MY ----
    bf16x8 af2[4][3];
    #pragma unroll
    for (int mt = 0; mt < 4; ++mt)
        #pragma unroll
        for (int kk = 0; kk < 3; ++kk)
            af2[mt][kk] = *(const bf16x8*)&sm[MYG_E + (mt*16+l16)*104 + kk*32 + quad*8];
    __syncthreads();   // MY dead; MG overlays

    f32x4 acc2[6];
    #pragma unroll
    for (int n = 0; n < 6; ++n) acc2[n] = (f32x4){};

    for (int ci = 0; ci < 3; ++ci) {
        #pragma unroll
        for (int rep = 0; rep < 2; ++rep) {
            const int ntl = wave + rep*4;
            const int ub  = ci*128 + ntl*16;
            bf16x8 bw[3];
            #pragma unroll
            for (int kk = 0; kk < 3; ++kk)
                bw[kk] = *(const bf16x8*)(wfc1 + (size_t)(ub + l16)*96 + kk*32 + quad*8);
            const f32x4 b4 = *(const f32x4*)&fc1b[ub + quad*4];
            #pragma unroll
            for (int mt = 0; mt < 4; ++mt) {
                f32x4 acc = {};
                #pragma unroll
                for (int kk = 0; kk < 3; ++kk) acc = mfma16(bw[kk], af2[mt][kk], acc);
                bf16x4 g4;
                #pragma unroll
                for (int r = 0; r < 4; ++r) {
                    // gelu(x) = x * sigmoid(1.5957691x + 0.0713548x^3)
                    float tv = acc[r] + b4[r];
                    float uu = tv*tv;
                    float w  = tv*fmaf(-0.0713548165f, uu, -1.5957691216f);
                    float e  = __expf(w);
                    g4[r] = (bf16)(tv*__builtin_amdgcn_rcpf(1.f + e));
                }
                *(bf16x4*)&sm[MYG_E + (mt*16 + l16)*136 + ntl*16 + quad*4] = g4;
            }
        }
        __syncthreads();
        bf16x8 ag[4];
        #pragma unroll
        for (int kq = 0; kq < 4; ++kq)
            ag[kq] = *(const bf16x8*)&sm[MYG_E + (wave*16+l16)*136 + kq*32 + quad*8];
        #pragma unroll
        for (int nt2 = 0; nt2 < 6; ++nt2) {
            const int c = nt2*16 + l16;
            #pragma unroll
            for (int kq = 0; kq < 4; ++kq) {
                bf16x8 bw = *(const bf16x8*)(wfc2 + (size_t)c*384 + ci*128 + kq*32 + quad*8);
                acc2[nt2] = mfma16(ag[kq], bw, acc2[nt2]);
            }
        }
        if (ci < 2) __syncthreads();   // G rewritten next chunk
    }

    // ---- out = h + mlp (+fc2b); h from AXO; direct NCHW f32x4 store ----
    {
        const int row = wave*16 + quad*4;             // 4 consecutive window tokens, same row
        const int gh  = (wh*WS_ + (row>>3) + SHIFT_) & (H_-1);
        const int gw0 = (ww*WS_ + (row&7)  + SHIFT_) & (W_-1);   // 4-aligned
        #pragma unroll
        for (int nt2 = 0; nt2 < 6; ++nt2) {
            const int c = nt2*16 + l16;
            const float bias = fc2b[c];
            f32x4 o;
            #pragma unroll
            for (int r = 0; r < 4; ++r)
                o[r] = acc2[nt2][r] + bias + (float)sm[AXO_E + (row+r)*104 + c];
            *(f32x4*)(out + (size_t)(b*96 + c)*HW_ + gh*W_ + gw0) = o;
        }
    }
}

extern "C" void kernel_launch(void* const* d_in, const int* in_sizes, int n_in,
                              void* d_out, int out_size, void* d_ws, size_t ws_size,
                              hipStream_t stream) {
    const float* x      = (const float*)d_in[0];
    const float* norm_w = (const float*)d_in[1];
    const float* norm_b = (const float*)d_in[2];
    const float* qkv_w  = (const float*)d_in[3];
    const float* qkv_b  = (const float*)d_in[4];
    const float* proj_w = (const float*)d_in[5];
    const float* proj_b = (const float*)d_in[6];
    const float* rpb    = (const float*)d_in[7];
    const float* n2w    = (const float*)d_in[8];
    const float* n2b    = (const float*)d_in[9];
    const float* fc1w   = (const float*)d_in[10];
    const float* fc1b   = (const float*)d_in[11];
    const float* fc2w   = (const float*)d_in[12];
    const float* fc2b   = (const float*)d_in[13];

    float* outp = (float*)d_out;
    char*  ws   = (char*)d_ws;
    bf16*  wa   = (bf16*)ws;                         // weight arena
    float* bq2  = (float*)(ws + (size_t)WSUM_E*2);

    prepw_kernel<<<WBLKS, 256, 0, stream>>>(qkv_w, qkv_b, proj_w, fc1w, fc2w, wa, bq2);
    fused_kernel<<<B_*1024, 256, 0, stream>>>(x, norm_w, norm_b,
                                              wa, bq2,
                                              wa + WQ2_E, proj_b, rpb,
                                              n2w, n2b,
                                              wa + WQ2_E + WPR_E, fc1b,
                                              wa + WQ2_E + WPR_E + WF1_E, fc2b,
                                              outp);
}

// Round 12
// 481.696 us; speedup vs baseline: 1.1659x; 1.0052x over previous
//
#include <hip/hip_runtime.h>
#include <hip/hip_bf16.h>
#include <math.h>

// ---- problem constants ----
constexpr int B_    = 4;
constexpr int C_    = 96;
constexpr int H_    = 256;
constexpr int W_    = 256;
constexpr int WS_   = 8;
constexpr int NH_   = 4;
constexpr int SHIFT_= 4;
constexpr int HD_   = 24;
constexpr int HW_   = H_*W_;
constexpr float EPS_   = 1e-6f;
constexpr float SCALE_ = 0.20412414523193150f; // 24^-0.5

using bf16   = __bf16;
using bf16x8 = __attribute__((ext_vector_type(8))) __bf16;
using bf16x4 = __attribute__((ext_vector_type(4))) __bf16;
using f32x4  = __attribute__((ext_vector_type(4))) float;

__device__ __forceinline__ f32x4 mfma16(bf16x8 a, bf16x8 b, f32x4 c) {
    return __builtin_amdgcn_mfma_f32_16x16x32_bf16(a, b, c, 0, 0, 0);
}

// ---- weight arena (bf16 elements) ----
constexpr int    WQ2_E   = 320*96;                        // per-head q|k|v|pad
constexpr int    WPR_E   = 96*96;
constexpr int    WF1_E   = 384*96;
constexpr int    WF2_E   = 96*384;
constexpr int    WSUM_E  = WQ2_E + WPR_E + WF1_E + WF2_E; // 113664
constexpr int    NBQ     = 320;
constexpr int    WBLKS   = (WSUM_E + NBQ + 255)/256;      // 446

__global__ __launch_bounds__(256) void prepw_kernel(
    const float* __restrict__ qkv_w, const float* __restrict__ qkv_b,
    const float* __restrict__ proj_w, const float* __restrict__ fc1w,
    const float* __restrict__ fc2w,
    bf16* __restrict__ warena, float* __restrict__ bq2)
{
    int i = blockIdx.x*256 + threadIdx.x;
    if (i < WQ2_E) {
        int R = i/96, c = i%96;
        int h = R/80, s = R%80;
        float v;
        if      (s < 24) v = qkv_w[(h*24+s)*96 + c] * SCALE_;
        else if (s < 48) v = qkv_w[(96 + h*24 + s-24)*96 + c];
        else if (s < 72) v = qkv_w[(192 + h*24 + s-48)*96 + c];
        else             v = 0.f;
        warena[i] = (bf16)v;
    } else if (i < WQ2_E + WPR_E) {
        warena[i] = (bf16)proj_w[i - WQ2_E];
    } else if (i < WQ2_E + WPR_E + WF1_E) {
        warena[i] = (bf16)fc1w[i - WQ2_E - WPR_E];
    } else if (i < WSUM_E) {
        warena[i] = (bf16)fc2w[i - WQ2_E - WPR_E - WF1_E];
    } else if (i < WSUM_E + NBQ) {
        int j = i - WSUM_E;
        int h = j/80, s = j%80;
        float v;
        if      (s < 24) v = qkv_b[h*24+s] * SCALE_;
        else if (s < 48) v = qkv_b[96 + h*24 + s-24];
        else if (s < 72) v = qkv_b[192 + h*24 + s-48];
        else             v = 0.f;
        bq2[j] = v;
    }
}

// ---- fused kernel LDS layout (bf16 element offsets) ----
// AXO [64][104] : x-bf16 -> ln1 (in place) -> attn-out -> proj-out -> h
// B0/B1: double-buffered per-head QKV: Q[64][40] | K[64][24] | V^T[24][72]
// P  [64][72] : softmax output (WAVE-PRIVATE rows 16w..16w+15)
// MLP: MY [64][104] then MG [64][136] overlay B0 region (dead after attn).
//
// Sync ledger (audited r12): wave w owns token rows 16w..+15 through
// softmax->P->PV->proj->h->LN2 (all wave-private; in-wave LDS RAW ordered by
// lgkmcnt). Cross-wave hazards: qkv(nb) visible to next scores + PV(cb) reads
// done before qkv(h+2) overwrite -> ONE loop-end barrier per head. After the
// h=3 barrier no wave touches B0/B1/P -> MY overlay safe without post-proj
// barrier.
constexpr int AXO_E = 0;
constexpr int B0_E  = 6656;
constexpr int B1_E  = 12480;            // B0_E + 5824
constexpr int P_E   = 18304;            // B1_E + 5824
constexpr int MYG_E = 6656;             // MLP overlay (B0/B1/P dead)
constexpr int SM_E  = 22912;            // el = 45824 B -> 3 blocks/CU

__global__ __launch_bounds__(256, 2) void fused_kernel(
    const float* __restrict__ x,       // [B,C,H,W] f32
    const float* __restrict__ norm_w, const float* __restrict__ norm_b,
    const bf16*  __restrict__ wq2,     // [320][96] per-head q|k|v|pad
    const float* __restrict__ bq2,     // [320]
    const bf16*  __restrict__ wproj,   // [96][96]
    const float* __restrict__ proj_b,
    const float* __restrict__ rpb,     // [225][4] f32
    const float* __restrict__ n2w, const float* __restrict__ n2b,
    const bf16*  __restrict__ wfc1, const float* __restrict__ fc1b,
    const bf16*  __restrict__ wfc2, const float* __restrict__ fc2b,
    float* __restrict__ out)           // [B,C,H,W] f32
{
    __shared__ __align__(16) bf16 sm[SM_E];

    const int tid  = threadIdx.x;
    const int wave = tid >> 6, lane = tid & 63;
    const int l16  = lane & 15, quad = lane >> 4;
    const int t  = tid >> 2, qa = tid & 3;
    const int qrow0 = wave*16;

    // XCD-chunked bijective swizzle (4096 % 8 == 0): adjacent windows share
    // 64B lines of x/out and land on the same XCD's L2 -> partial lines merge.
    const int blk = (blockIdx.x & 7)*512 + (blockIdx.x >> 3);
    const int b   = blk >> 10;
    const int wid = blk & 1023;
    const int wh  = wid >> 5, ww = wid & 31;

    // ---- Phase A: gather window's x (f32 NCHW, shifted+wrapped) -> AXO bf16 ----
    #pragma unroll
    for (int it = 0; it < 6; ++it) {
        const int i2  = it*256 + tid;          // 0..1535
        const int c   = i2 >> 4;               // 0..95
        const int rem = i2 & 15;
        const int wi  = rem >> 1;
        const int wj4 = (rem & 1)*4;
        const int gh  = (wh*WS_ + wi + SHIFT_) & (H_-1);
        const int gw0 = (ww*WS_ + wj4 + SHIFT_) & (W_-1);  // 4-aligned, no 16B crossing
        f32x4 v4 = *(const f32x4*)(x + (size_t)(b*96 + c)*HW_ + gh*W_ + gw0);
        #pragma unroll
        for (int j = 0; j < 4; ++j)
            sm[AXO_E + (wi*8 + wj4 + j)*104 + c] = (bf16)v4[j];
    }
    __syncthreads();

    // ---- Phase B0: LN1 in place (thread-local rows); x kept in REGISTERS ----
    bf16x8 xreg[3];                    // this thread's 24 x channels (residual)
    {
        float v[24]; float mu = 0.f, ss = 0.f;
        #pragma unroll
        for (int k = 0; k < 3; ++k) {
            xreg[k] = *(const bf16x8*)&sm[AXO_E + t*104 + qa*24 + k*8];
            #pragma unroll
            for (int j = 0; j < 8; ++j) {
                v[k*8+j] = (float)xreg[k][j];
                mu += v[k*8+j]; ss += v[k*8+j]*v[k*8+j];
            }
        }
        mu += __shfl_xor(mu,1); mu += __shfl_xor(mu,2);
        ss += __shfl_xor(ss,1); ss += __shfl_xor(ss,2);
        mu *= (1.f/C_);
        float rstd = rsqrtf(ss*(1.f/C_) - mu*mu + EPS_);
        #pragma unroll
        for (int k = 0; k < 3; ++k) {
            bf16x8 ln8;
            #pragma unroll
            for (int j = 0; j < 8; ++j) {
                const int c = qa*24 + k*8 + j;
                ln8[j] = (bf16)((v[k*8+j]-mu)*rstd*norm_w[c] + norm_b[c]);
            }
            *(bf16x8*)&sm[AXO_E + t*104 + qa*24 + k*8] = ln8;
        }
    }
    __syncthreads();   // AXO now holds xln

    // zero Q pad cols 24..31 of BOTH buffers (QKV stores never touch them)
    if (tid < 128) {
        bf16x8 z = {};
        const int bb = (tid >> 6) ? B1_E : B0_E;
        *(bf16x8*)&sm[bb + (tid & 63)*40 + 24] = z;
    }

    // A-frags of LN'd x, kept in registers for all heads
    bf16x8 af[4][3];
    #pragma unroll
    for (int mt = 0; mt < 4; ++mt)
        #pragma unroll
        for (int kk = 0; kk < 3; ++kk)
            af[mt][kk] = *(const bf16x8*)&sm[AXO_E + (mt*16+l16)*104 + kk*32 + quad*8];

    // ---- hoisted mask/bias index precompute (head-invariant) ----
    int   rix[4][4];   // rpb row index * NH_
    float mb [4][4];   // 0 or -100 shift mask term
    #pragma unroll
    for (int kt = 0; kt < 4; ++kt) {
        const int key = kt*16 + l16;
        const int ki = key >> 3, kj = key & 7;
        const int labk = (((wh*8+ki) >= H_-WS_) + ((wh*8+ki) >= H_-SHIFT_))*3
                       +  ((ww*8+kj) >= W_-WS_) + ((ww*8+kj) >= W_-SHIFT_);
        #pragma unroll
        for (int r = 0; r < 4; ++r) {
            const int q = qrow0 + quad*4 + r;
            const int ti = q >> 3, tj = q & 7;
            const int labq = (((wh*8+ti) >= H_-WS_) + ((wh*8+ti) >= H_-SHIFT_))*3
                           +  ((ww*8+tj) >= W_-WS_) + ((ww*8+tj) >= W_-SHIFT_);
            rix[kt][r] = ((ti - ki + 7)*15 + (tj - kj + 7))*NH_;
            mb [kt][r] = (labk != labq) ? -100.f : 0.f;
        }
    }

    // per-head QKV emitter: 5 N-tiles (80 cols: q24|k24|v24|pad8) over 4 waves
    auto qkv_head = [&](int hh, int qb) {
        #pragma unroll
        for (int jt = 0; jt < 5; ++jt) {
            if (((hh*5 + jt) & 3) != wave) continue;
            const int s   = jt*16 + l16;           // 0..79 within head
            const int row = hh*80 + s;
            bf16x8 bw[3];
            #pragma unroll
            for (int kk = 0; kk < 3; ++kk)
                bw[kk] = *(const bf16x8*)(wq2 + (size_t)row*96 + kk*32 + quad*8);
            const float bias = bq2[row];
            #pragma unroll
            for (int mt = 0; mt < 4; ++mt) {
                f32x4 acc = {};
                #pragma unroll
                for (int kk = 0; kk < 3; ++kk) acc = mfma16(af[mt][kk], bw[kk], acc);
                const int tb = mt*16 + quad*4;
                if (s < 24) {
                    #pragma unroll
                    for (int r = 0; r < 4; ++r)
                        sm[qb + (tb+r)*40 + s] = (bf16)(acc[r] + bias);
                } else if (s < 48) {
                    #pragma unroll
                    for (int r = 0; r < 4; ++r)
                        sm[qb + 2560 + (tb+r)*24 + (s-24)] = (bf16)(acc[r] + bias);
                } else if (s < 72) {
                    bf16x4 pv;
                    #pragma unroll
                    for (int r = 0; r < 4; ++r) pv[r] = (bf16)(acc[r] + bias);
                    *(bf16x4*)&sm[qb + 4096 + (s-48)*72 + tb] = pv;
                }
            }
        }
    };

    // prologue: head 0 into buffer 0
    qkv_head(0, B0_E);
    __syncthreads();

    for (int h = 0; h < NH_; ++h) {
        const int cb = (h & 1) ? B1_E : B0_E;   // current buffer
        const int nb = (h & 1) ? B0_E : B1_E;   // next buffer

        // ---- issue next head's QKV (hides weight-load latency under scores) ----
        if (h < NH_-1) qkv_head(h+1, nb);

        // ---- scores + softmax (wave owns queries qrow0..+15) ----
        bf16x8 aq = *(const bf16x8*)&sm[cb + (qrow0 + l16)*40 + quad*8];
        f32x4 accS[4];
        #pragma unroll
        for (int kt = 0; kt < 4; ++kt) {
            bf16x8 bk = *(const bf16x8*)&sm[cb + 2560 + (kt*16+l16)*24 + quad*8];
            f32x4 z = {};
            accS[kt] = mfma16(aq, bk, z);
        }
        float s_[4][4];
        #pragma unroll
        for (int kt = 0; kt < 4; ++kt)
            #pragma unroll
            for (int r = 0; r < 4; ++r)
                s_[kt][r] = accS[kt][r] + rpb[rix[kt][r] + h] + mb[kt][r];
        #pragma unroll
        for (int r = 0; r < 4; ++r) {
            float m = fmaxf(fmaxf(s_[0][r], s_[1][r]), fmaxf(s_[2][r], s_[3][r]));
            m = fmaxf(m, __shfl_xor(m,1)); m = fmaxf(m, __shfl_xor(m,2));
            m = fmaxf(m, __shfl_xor(m,4)); m = fmaxf(m, __shfl_xor(m,8));
            float su = 0.f;
            #pragma unroll
            for (int kt = 0; kt < 4; ++kt) { s_[kt][r] = __expf(s_[kt][r]-m); su += s_[kt][r]; }
            su += __shfl_xor(su,1); su += __shfl_xor(su,2);
            su += __shfl_xor(su,4); su += __shfl_xor(su,8);
            const float inv = 1.f/su;
            #pragma unroll
            for (int kt = 0; kt < 4; ++kt)
                sm[P_E + (qrow0 + quad*4 + r)*72 + kt*16 + l16] = (bf16)(s_[kt][r]*inv);
        }
        // NO barrier: P rows are wave-private (written & read by this wave only);
        // V(cb) was synced by the previous iteration's loop-end barrier.

        // ---- PV -> attn-out cols h*24..+23 of AXO (wave-private rows) ----
        bf16x8 ap0 = *(const bf16x8*)&sm[P_E + (qrow0+l16)*72 + quad*8];
        bf16x8 ap1 = *(const bf16x8*)&sm[P_E + (qrow0+l16)*72 + 32 + quad*8];
        #pragma unroll
        for (int nt2 = 0; nt2 < 2; ++nt2) {
            const int d = nt2*16 + l16;
            bf16x8 bv0 = *(const bf16x8*)&sm[cb + 4096 + d*72 + quad*8];
            bf16x8 bv1 = *(const bf16x8*)&sm[cb + 4096 + d*72 + 32 + quad*8];
            f32x4 acc = {};
            acc = mfma16(ap0, bv0, acc);
            acc = mfma16(ap1, bv1, acc);
            if (d < HD_) {
                #pragma unroll
                for (int r = 0; r < 4; ++r)
                    sm[AXO_E + (qrow0 + quad*4 + r)*104 + h*24 + d] = (bf16)acc[r];
            }
        }
        __syncthreads();   // loop-end: nb visible to next scores; cb reads done
    }

    // ---- proj (wave-private: reads/writes AXO rows qrow0..+15 only) ----
    {
        bf16x8 ao[3];
        #pragma unroll
        for (int kk = 0; kk < 3; ++kk)
            ao[kk] = *(const bf16x8*)&sm[AXO_E + (qrow0 + l16)*104 + kk*32 + quad*8];
        for (int nt = 0; nt < 6; ++nt) {
            const int oc = nt*16 + l16;
            bf16x8 bw[3];
            #pragma unroll
            for (int kk = 0; kk < 3; ++kk)
                bw[kk] = *(const bf16x8*)(wproj + (size_t)oc*96 + kk*32 + quad*8);
            f32x4 acc = {};
            #pragma unroll
            for (int kk = 0; kk < 3; ++kk) acc = mfma16(ao[kk], bw[kk], acc);
            #pragma unroll
            for (int r = 0; r < 4; ++r)
                sm[AXO_E + (qrow0 + quad*4 + r)*104 + oc] = (bf16)acc[r];
        }
    }
    // NO barrier: h/LN2 reads AXO rows t in [16*wave, 16*wave+16) -- same wave
    // that proj wrote them; MY overlay of B0/B1 is fenced by the h=3 barrier.

    // ---- h = x(regs) + proj-out + proj_b -> AXO (bf16 h); LN2 -> MY ----
    {
        float hv[24]; float mu = 0.f, ss = 0.f;
        #pragma unroll
        for (int k = 0; k < 3; ++k) {
            bf16x8 po = *(const bf16x8*)&sm[AXO_E + t*104 + qa*24 + k*8];
            bf16x8 h8;
            #pragma unroll
            for (int j = 0; j < 8; ++j) {
                float hf = (float)xreg[k][j] + (float)po[j] + proj_b[qa*24 + k*8 + j];
                h8[j] = (bf16)hf;
                float hb = (float)h8[j];      // LN2 sees bf16-rounded h (matches prior impl)
                hv[k*8+j] = hb;
                mu += hb; ss += hb*hb;
            }
            *(bf16x8*)&sm[AXO_E + t*104 + qa*24 + k*8] = h8;
        }
        mu += __shfl_xor(mu,1); mu += __shfl_xor(mu,2);
        ss += __shfl_xor(ss,1); ss += __shfl_xor(ss,2);
        mu *= (1.f/C_);
        float rstd = rsqrtf(ss*(1.f/C_) - mu*mu + EPS_);
        #pragma unroll
        for (int k = 0; k < 3; ++k) {
            bf16x8 o;
            #pragma unroll
            for (int j = 0; j < 8; ++j) {
                const int c = qa*24 + k*8 + j;
                o[j] = (bf16)((hv[k*8+j]-mu)*rstd*n2w[c] + n2b[c]);
            }
            *(bf16x8*)&sm[MYG_E + t*104 + qa*24 + k*8] = o;   // MY overlays dead attn scratch
        }
    }
    __syncthreads();   // af2 reads ALL MY rows (cross-wave)

    // ---- MLP: af2 from MY ----
    bf16x8 af2[4][3];
    #pragma unroll
    for (int mt = 0; mt < 4; ++mt)
        #pragma unroll
        for (int kk = 0; kk < 3; ++kk)
            af2[mt][kk] = *(const bf16x8*)&sm[MYG_E + (mt*16+l16)*104 + kk*32 + quad*8];
    __syncthreads();   // MY dead; MG overlays

    f32x4 acc2[6];
    #pragma unroll
    for (int n = 0; n < 6; ++n) acc2[n] = (f32x4){};

    for (int ci = 0; ci < 3; ++ci) {
        #pragma unroll
        for (int rep = 0; rep < 2; ++rep) {
            const int ntl = wave + rep*4;
            const int ub  = ci*128 + ntl*16;
            bf16x8 bw[3];
            #pragma unroll
            for (int kk = 0; kk < 3; ++kk)
                bw[kk] = *(const bf16x8*)(wfc1 + (size_t)(ub + l16)*96 + kk*32 + quad*8);
            const f32x4 b4 = *(const f32x4*)&fc1b[ub + quad*4];
            #pragma unroll
            for (int mt = 0; mt < 4; ++mt) {
                f32x4 acc = {};
                #pragma unroll
                for (int kk = 0; kk < 3; ++kk) acc = mfma16(bw[kk], af2[mt][kk], acc);
                bf16x4 g4;
                #pragma unroll
                for (int r = 0; r < 4; ++r) {
                    // gelu(x) = x * sigmoid(1.5957691x + 0.0713548x^3)
                    float tv = acc[r] + b4[r];
                    float uu = tv*tv;
                    float w  = tv*fmaf(-0.0713548165f, uu, -1.5957691216f);
                    float e  = __expf(w);
                    g4[r] = (bf16)(tv*__builtin_amdgcn_rcpf(1.f + e));
                }
                *(bf16x4*)&sm[MYG_E + (mt*16 + l16)*136 + ntl*16 + quad*4] = g4;
            }
        }
        __syncthreads();
        bf16x8 ag[4];
        #pragma unroll
        for (int kq = 0; kq < 4; ++kq)
            ag[kq] = *(const bf16x8*)&sm[MYG_E + (wave*16+l16)*136 + kq*32 + quad*8];
        #pragma unroll
        for (int nt2 = 0; nt2 < 6; ++nt2) {
            const int c = nt2*16 + l16;
            #pragma unroll
            for (int kq = 0; kq < 4; ++kq) {
                bf16x8 bw = *(const bf16x8*)(wfc2 + (size_t)c*384 + ci*128 + kq*32 + quad*8);
                acc2[nt2] = mfma16(ag[kq], bw, acc2[nt2]);
            }
        }
        if (ci < 2) __syncthreads();   // G rewritten next chunk
    }

    // ---- out = h + mlp (+fc2b); h from AXO; direct NCHW f32x4 store ----
    {
        const int row = wave*16 + quad*4;             // 4 consecutive window tokens, same row
        const int gh  = (wh*WS_ + (row>>3) + SHIFT_) & (H_-1);
        const int gw0 = (ww*WS_ + (row&7)  + SHIFT_) & (W_-1);   // 4-aligned
        #pragma unroll
        for (int nt2 = 0; nt2 < 6; ++nt2) {
            const int c = nt2*16 + l16;
            const float bias = fc2b[c];
            f32x4 o;
            #pragma unroll
            for (int r = 0; r < 4; ++r)
                o[r] = acc2[nt2][r] + bias + (float)sm[AXO_E + (row+r)*104 + c];
            *(f32x4*)(out + (size_t)(b*96 + c)*HW_ + gh*W_ + gw0) = o;
        }
    }
}

extern "C" void kernel_launch(void* const* d_in, const int* in_sizes, int n_in,
                              void* d_out, int out_size, void* d_ws, size_t ws_size,
                              hipStream_t stream) {
    const float* x      = (const float*)d_in[0];
    const float* norm_w = (const float*)d_in[1];
    const float* norm_b = (const float*)d_in[2];
    const float* qkv_w  = (const float*)d_in[3];
    const float* qkv_b  = (const float*)d_in[4];
    const float* proj_w = (const float*)d_in[5];
    const float* proj_b = (const float*)d_in[6];
    const float* rpb    = (const float*)d_in[7];
    const float* n2w    = (const float*)d_in[8];
    const float* n2b    = (const float*)d_in[9];
    const float* fc1w   = (const float*)d_in[10];
    const float* fc1b   = (const float*)d_in[11];
    const float* fc2w   = (const float*)d_in[12];
    const float* fc2b   = (const float*)d_in[13];

    float* outp = (float*)d_out;
    char*  ws   = (char*)d_ws;
    bf16*  wa   = (bf16*)ws;                         // weight arena
    float* bq2  = (float*)(ws + (size_t)WSUM_E*2);

    prepw_kernel<<<WBLKS, 256, 0, stream>>>(qkv_w, qkv_b, proj_w, fc1w, fc2w, wa, bq2);
    fused_kernel<<<B_*1024, 256, 0, stream>>>(x, norm_w, norm_b,
                                              wa, bq2,
                                              wa + WQ2_E, proj_b, rpb,
                                              n2w, n2b,
                                              wa + WQ2_E + WPR_E, fc1b,
                                              wa + WQ2_E + WPR_E + WF1_E, fc2b,
                                              outp);
}

// Round 13
// 481.547 us; speedup vs baseline: 1.1662x; 1.0003x over previous
//
#include <hip/hip_runtime.h>
#include <hip/hip_bf16.h>
#include <math.h>

// ---- problem constants ----
constexpr int B_    = 4;
constexpr int C_    = 96;
constexpr int H_    = 256;
constexpr int W_    = 256;
constexpr int WS_   = 8;
constexpr int NH_   = 4;
constexpr int SHIFT_= 4;
constexpr int HD_   = 24;
constexpr int HW_   = H_*W_;
constexpr float EPS_   = 1e-6f;
constexpr float SCALE_ = 0.20412414523193150f; // 24^-0.5

using bf16   = __bf16;
using bf16x8 = __attribute__((ext_vector_type(8))) __bf16;
using bf16x4 = __attribute__((ext_vector_type(4))) __bf16;
using f32x4  = __attribute__((ext_vector_type(4))) float;

__device__ __forceinline__ f32x4 mfma16(bf16x8 a, bf16x8 b, f32x4 c) {
    return __builtin_amdgcn_mfma_f32_16x16x32_bf16(a, b, c, 0, 0, 0);
}

// ---- weight arena (bf16 elements) ----
constexpr int    WQ2_E   = 320*96;                        // per-head q|k|v|pad
constexpr int    WPR_E   = 96*96;
constexpr int    WF1_E   = 384*96;
constexpr int    WF2_E   = 96*384;
constexpr int    WSUM_E  = WQ2_E + WPR_E + WF1_E + WF2_E; // 113664
constexpr int    NBQ     = 320;
constexpr int    WBLKS   = (WSUM_E + NBQ + 255)/256;      // 446

__global__ __launch_bounds__(256) void prepw_kernel(
    const float* __restrict__ qkv_w, const float* __restrict__ qkv_b,
    const float* __restrict__ proj_w, const float* __restrict__ fc1w,
    const float* __restrict__ fc2w,
    bf16* __restrict__ warena, float* __restrict__ bq2)
{
    int i = blockIdx.x*256 + threadIdx.x;
    if (i < WQ2_E) {
        int R = i/96, c = i%96;
        int h = R/80, s = R%80;
        float v;
        if      (s < 24) v = qkv_w[(h*24+s)*96 + c] * SCALE_;
        else if (s < 48) v = qkv_w[(96 + h*24 + s-24)*96 + c];
        else if (s < 72) v = qkv_w[(192 + h*24 + s-48)*96 + c];
        else             v = 0.f;
        warena[i] = (bf16)v;
    } else if (i < WQ2_E + WPR_E) {
        warena[i] = (bf16)proj_w[i - WQ2_E];
    } else if (i < WQ2_E + WPR_E + WF1_E) {
        warena[i] = (bf16)fc1w[i - WQ2_E - WPR_E];
    } else if (i < WSUM_E) {
        warena[i] = (bf16)fc2w[i - WQ2_E - WPR_E - WF1_E];
    } else if (i < WSUM_E + NBQ) {
        int j = i - WSUM_E;
        int h = j/80, s = j%80;
        float v;
        if      (s < 24) v = qkv_b[h*24+s] * SCALE_;
        else if (s < 48) v = qkv_b[96 + h*24 + s-24];
        else if (s < 72) v = qkv_b[192 + h*24 + s-48];
        else             v = 0.f;
        bq2[j] = v;
    }
}

// ---- fused kernel LDS layout (bf16 element offsets) ----
// AXO [64][104] : x-bf16 -> ln1 (in place) -> attn-out -> proj-out -> h
// B0/B1: double-buffered per-head QKV: Q[64][40] | K[64][24] | V^T[24][72]
// P  [64][72] : softmax output (WAVE-PRIVATE rows 16w..16w+15)
// MLP: MY [64][104] then MG [64][136] overlay B0 region (dead after attn).
//
// Sync ledger (r12, verified): wave w owns token rows 16w..+15 through
// softmax->P->PV->proj->h->LN2; one loop-end barrier per head covers the
// only cross-wave hazards (nb visible to next scores, cb reads done).
//
// r13: OUTER LOOPS NOT UNROLLED (#pragma unroll 1 on head/ci/nt loops).
// Theory: fully-unrolled body (~40KB+) thrashes the 32KB per-CU I$ --
// straight-line code is fetched once per wave with no reuse, and the
// resulting fetch stalls are invisible in VALU/MFMA/LDS counters
// (matching the all-pipes-idle signature). Looped bodies stay I$-hot.
constexpr int AXO_E = 0;
constexpr int B0_E  = 6656;
constexpr int B1_E  = 12480;            // B0_E + 5824
constexpr int P_E   = 18304;            // B1_E + 5824
constexpr int MYG_E = 6656;             // MLP overlay (B0/B1/P dead)
constexpr int SM_E  = 22912;            // el = 45824 B

__global__ __launch_bounds__(256, 2) void fused_kernel(
    const float* __restrict__ x,       // [B,C,H,W] f32
    const float* __restrict__ norm_w, const float* __restrict__ norm_b,
    const bf16*  __restrict__ wq2,     // [320][96] per-head q|k|v|pad
    const float* __restrict__ bq2,     // [320]
    const bf16*  __restrict__ wproj,   // [96][96]
    const float* __restrict__ proj_b,
    const float* __restrict__ rpb,     // [225][4] f32
    const float* __restrict__ n2w, const float* __restrict__ n2b,
    const bf16*  __restrict__ wfc1, const float* __restrict__ fc1b,
    const bf16*  __restrict__ wfc2, const float* __restrict__ fc2b,
    float* __restrict__ out)           // [B,C,H,W] f32
{
    __shared__ __align__(16) bf16 sm[SM_E];

    const int tid  = threadIdx.x;
    const int wave = tid >> 6, lane = tid & 63;
    const int l16  = lane & 15, quad = lane >> 4;
    const int t  = tid >> 2, qa = tid & 3;
    const int qrow0 = wave*16;

    // XCD-chunked bijective swizzle (4096 % 8 == 0): adjacent windows share
    // 64B lines of x/out and land on the same XCD's L2 -> partial lines merge.
    const int blk = (blockIdx.x & 7)*512 + (blockIdx.x >> 3);
    const int b   = blk >> 10;
    const int wid = blk & 1023;
    const int wh  = wid >> 5, ww = wid & 31;

    // ---- Phase A: gather window's x (f32 NCHW, shifted+wrapped) -> AXO bf16 ----
    #pragma unroll
    for (int it = 0; it < 6; ++it) {
        const int i2  = it*256 + tid;          // 0..1535
        const int c   = i2 >> 4;               // 0..95
        const int rem = i2 & 15;
        const int wi  = rem >> 1;
        const int wj4 = (rem & 1)*4;
        const int gh  = (wh*WS_ + wi + SHIFT_) & (H_-1);
        const int gw0 = (ww*WS_ + wj4 + SHIFT_) & (W_-1);  // 4-aligned, no 16B crossing
        f32x4 v4 = *(const f32x4*)(x + (size_t)(b*96 + c)*HW_ + gh*W_ + gw0);
        #pragma unroll
        for (int j = 0; j < 4; ++j)
            sm[AXO_E + (wi*8 + wj4 + j)*104 + c] = (bf16)v4[j];
    }
    __syncthreads();

    // ---- Phase B0: LN1 in place (thread-local rows); x kept in REGISTERS ----
    bf16x8 xreg[3];                    // this thread's 24 x channels (residual)
    {
        float v[24]; float mu = 0.f, ss = 0.f;
        #pragma unroll
        for (int k = 0; k < 3; ++k) {
            xreg[k] = *(const bf16x8*)&sm[AXO_E + t*104 + qa*24 + k*8];
            #pragma unroll
            for (int j = 0; j < 8; ++j) {
                v[k*8+j] = (float)xreg[k][j];
                mu += v[k*8+j]; ss += v[k*8+j]*v[k*8+j];
            }
        }
        mu += __shfl_xor(mu,1); mu += __shfl_xor(mu,2);
        ss += __shfl_xor(ss,1); ss += __shfl_xor(ss,2);
        mu *= (1.f/C_);
        float rstd = rsqrtf(ss*(1.f/C_) - mu*mu + EPS_);
        #pragma unroll
        for (int k = 0; k < 3; ++k) {
            bf16x8 ln8;
            #pragma unroll
            for (int j = 0; j < 8; ++j) {
                const int c = qa*24 + k*8 + j;
                ln8[j] = (bf16)((v[k*8+j]-mu)*rstd*norm_w[c] + norm_b[c]);
            }
            *(bf16x8*)&sm[AXO_E + t*104 + qa*24 + k*8] = ln8;
        }
    }
    __syncthreads();   // AXO now holds xln

    // zero Q pad cols 24..31 of BOTH buffers (QKV stores never touch them)
    if (tid < 128) {
        bf16x8 z = {};
        const int bb = (tid >> 6) ? B1_E : B0_E;
        *(bf16x8*)&sm[bb + (tid & 63)*40 + 24] = z;
    }

    // A-frags of LN'd x, kept in registers for all heads
    bf16x8 af[4][3];
    #pragma unroll
    for (int mt = 0; mt < 4; ++mt)
        #pragma unroll
        for (int kk = 0; kk < 3; ++kk)
            af[mt][kk] = *(const bf16x8*)&sm[AXO_E + (mt*16+l16)*104 + kk*32 + quad*8];

    // ---- hoisted mask/bias index precompute (head-invariant) ----
    int   rix[4][4];   // rpb row index * NH_
    float mb [4][4];   // 0 or -100 shift mask term
    #pragma unroll
    for (int kt = 0; kt < 4; ++kt) {
        const int key = kt*16 + l16;
        const int ki = key >> 3, kj = key & 7;
        const int labk = (((wh*8+ki) >= H_-WS_) + ((wh*8+ki) >= H_-SHIFT_))*3
                       +  ((ww*8+kj) >= W_-WS_) + ((ww*8+kj) >= W_-SHIFT_);
        #pragma unroll
        for (int r = 0; r < 4; ++r) {
            const int q = qrow0 + quad*4 + r;
            const int ti = q >> 3, tj = q & 7;
            const int labq = (((wh*8+ti) >= H_-WS_) + ((wh*8+ti) >= H_-SHIFT_))*3
                           +  ((ww*8+tj) >= W_-WS_) + ((ww*8+tj) >= W_-SHIFT_);
            rix[kt][r] = ((ti - ki + 7)*15 + (tj - kj + 7))*NH_;
            mb [kt][r] = (labk != labq) ? -100.f : 0.f;
        }
    }

    // per-head QKV emitter: 5 N-tiles (80 cols: q24|k24|v24|pad8) over 4 waves
    auto qkv_head = [&](int hh, int qb) {
        #pragma unroll
        for (int jt = 0; jt < 5; ++jt) {
            if (((hh*5 + jt) & 3) != wave) continue;
            const int s   = jt*16 + l16;           // 0..79 within head
            const int row = hh*80 + s;
            bf16x8 bw[3];
            #pragma unroll
            for (int kk = 0; kk < 3; ++kk)
                bw[kk] = *(const bf16x8*)(wq2 + (size_t)row*96 + kk*32 + quad*8);
            const float bias = bq2[row];
            #pragma unroll
            for (int mt = 0; mt < 4; ++mt) {
                f32x4 acc = {};
                #pragma unroll
                for (int kk = 0; kk < 3; ++kk) acc = mfma16(af[mt][kk], bw[kk], acc);
                const int tb = mt*16 + quad*4;
                if (s < 24) {
                    #pragma unroll
                    for (int r = 0; r < 4; ++r)
                        sm[qb + (tb+r)*40 + s] = (bf16)(acc[r] + bias);
                } else if (s < 48) {
                    #pragma unroll
                    for (int r = 0; r < 4; ++r)
                        sm[qb + 2560 + (tb+r)*24 + (s-24)] = (bf16)(acc[r] + bias);
                } else if (s < 72) {
                    bf16x4 pv;
                    #pragma unroll
                    for (int r = 0; r < 4; ++r) pv[r] = (bf16)(acc[r] + bias);
                    *(bf16x4*)&sm[qb + 4096 + (s-48)*72 + tb] = pv;
                }
            }
        }
    };

    // prologue: head 0 into buffer 0
    qkv_head(0, B0_E);
    __syncthreads();

    #pragma unroll 1   // keep loop body I$-resident (do NOT unroll 4x)
    for (int h = 0; h < NH_; ++h) {
        const int cb = (h & 1) ? B1_E : B0_E;   // current buffer
        const int nb = (h & 1) ? B0_E : B1_E;   // next buffer

        // ---- issue next head's QKV (hides weight-load latency under scores) ----
        if (h < NH_-1) qkv_head(h+1, nb);

        // ---- scores + softmax (wave owns queries qrow0..+15) ----
        bf16x8 aq = *(const bf16x8*)&sm[cb + (qrow0 + l16)*40 + quad*8];
        f32x4 accS[4];
        #pragma unroll
        for (int kt = 0; kt < 4; ++kt) {
            bf16x8 bk = *(const bf16x8*)&sm[cb + 2560 + (kt*16+l16)*24 + quad*8];
            f32x4 z = {};
            accS[kt] = mfma16(aq, bk, z);
        }
        float s_[4][4];
        #pragma unroll
        for (int kt = 0; kt < 4; ++kt)
            #pragma unroll
            for (int r = 0; r < 4; ++r)
                s_[kt][r] = accS[kt][r] + rpb[rix[kt][r] + h] + mb[kt][r];
        #pragma unroll
        for (int r = 0; r < 4; ++r) {
            float m = fmaxf(fmaxf(s_[0][r], s_[1][r]), fmaxf(s_[2][r], s_[3][r]));
            m = fmaxf(m, __shfl_xor(m,1)); m = fmaxf(m, __shfl_xor(m,2));
            m = fmaxf(m, __shfl_xor(m,4)); m = fmaxf(m, __shfl_xor(m,8));
            float su = 0.f;
            #pragma unroll
            for (int kt = 0; kt < 4; ++kt) { s_[kt][r] = __expf(s_[kt][r]-m); su += s_[kt][r]; }
            su += __shfl_xor(su,1); su += __shfl_xor(su,2);
            su += __shfl_xor(su,4); su += __shfl_xor(su,8);
            const float inv = 1.f/su;
            #pragma unroll
            for (int kt = 0; kt < 4; ++kt)
                sm[P_E + (qrow0 + quad*4 + r)*72 + kt*16 + l16] = (bf16)(s_[kt][r]*inv);
        }
        // NO barrier: P rows are wave-private; V(cb) synced by prior loop-end barrier.

        // ---- PV -> attn-out cols h*24..+23 of AXO (wave-private rows) ----
        bf16x8 ap0 = *(const bf16x8*)&sm[P_E + (qrow0+l16)*72 + quad*8];
        bf16x8 ap1 = *(const bf16x8*)&sm[P_E + (qrow0+l16)*72 + 32 + quad*8];
        #pragma unroll
        for (int nt2 = 0; nt2 < 2; ++nt2) {
            const int d = nt2*16 + l16;
            bf16x8 bv0 = *(const bf16x8*)&sm[cb + 4096 + d*72 + quad*8];
            bf16x8 bv1 = *(const bf16x8*)&sm[cb + 4096 + d*72 + 32 + quad*8];
            f32x4 acc = {};
            acc = mfma16(ap0, bv0, acc);
            acc = mfma16(ap1, bv1, acc);
            if (d < HD_) {
                #pragma unroll
                for (int r = 0; r < 4; ++r)
                    sm[AXO_E + (qrow0 + quad*4 + r)*104 + h*24 + d] = (bf16)acc[r];
            }
        }
        __syncthreads();   // loop-end: nb visible to next scores; cb reads done
    }

    // ---- proj (wave-private: reads/writes AXO rows qrow0..+15 only) ----
    {
        bf16x8 ao[3];
        #pragma unroll
        for (int kk = 0; kk < 3; ++kk)
            ao[kk] = *(const bf16x8*)&sm[AXO_E + (qrow0 + l16)*104 + kk*32 + quad*8];
        #pragma unroll 1   // keep body small (6 dynamic iterations)
        for (int nt = 0; nt < 6; ++nt) {
            const int oc = nt*16 + l16;
            bf16x8 bw[3];
            #pragma unroll
            for (int kk = 0; kk < 3; ++kk)
                bw[kk] = *(const bf16x8*)(wproj + (size_t)oc*96 + kk*32 + quad*8);
            f32x4 acc = {};
            #pragma unroll
            for (int kk = 0; kk < 3; ++kk) acc = mfma16(ao[kk], bw[kk], acc);
            #pragma unroll
            for (int r = 0; r < 4; ++r)
                sm[AXO_E + (qrow0 + quad*4 + r)*104 + oc] = (bf16)acc[r];
        }
    }
    // NO barrier: h/LN2 reads AXO rows of the same wave; MY overlay fenced by h=3 barrier.

    // ---- h = x(regs) + proj-out + proj_b -> AXO (bf16 h); LN2 -> MY ----
    {
        float hv[24]; float mu = 0.f, ss = 0.f;
        #pragma unroll
        for (int k = 0; k < 3; ++k) {
            bf16x8 po = *(const bf16x8*)&sm[AXO_E + t*104 + qa*24 + k*8];
            bf16x8 h8;
            #pragma unroll
            for (int j = 0; j < 8; ++j) {
                float hf = (float)xreg[k][j] + (float)po[j] + proj_b[qa*24 + k*8 + j];
                h8[j] = (bf16)hf;
                float hb = (float)h8[j];      // LN2 sees bf16-rounded h (matches prior impl)
                hv[k*8+j] = hb;
                mu += hb; ss += hb*hb;
            }
            *(bf16x8*)&sm[AXO_E + t*104 + qa*24 + k*8] = h8;
        }
        mu += __shfl_xor(mu,1); mu += __shfl_xor(mu,2);
        ss += __shfl_xor(ss,1); ss += __shfl_xor(ss,2);
        mu *= (1.f/C_);
        float rstd = rsqrtf(ss*(1.f/C_) - mu*mu + EPS_);
        #pragma unroll
        for (int k = 0; k < 3; ++k) {
            bf16x8 o;
            #pragma unroll
            for (int j = 0; j < 8; ++j) {
                const int c = qa*24 + k*8 + j;
                o[j] = (bf16)((hv[k*8+j]-mu)*rstd*n2w[c] + n2b[c]);
            }
            *(bf16x8*)&sm[MYG_E + t*104 + qa*24 + k*8] = o;   // MY overlays dead attn scratch
        }
    }
    __syncthreads();   // af2 reads ALL MY rows (cross-wave)

    // ---- MLP: af2 from MY ----
    bf16x8 af2[4][3];
    #pragma unroll
    for (int mt = 0; mt < 4; ++mt)
        #pragma unroll
        for (int kk = 0; kk < 3; ++kk)
            af2[mt][kk] = *(const bf16x8*)&sm[MYG_E + (mt*16+l16)*104 + kk*32 + quad*8];
    __syncthreads();   // MY dead; MG overlays

    f32x4 acc2[6];
    #pragma unroll
    for (int n = 0; n < 6; ++n) acc2[n] = (f32x4){};

    #pragma unroll 1   // keep chunk body I$-resident (do NOT unroll 3x)
    for (int ci = 0; ci < 3; ++ci) {
        #pragma unroll
        for (int rep = 0; rep < 2; ++rep) {
            const int ntl = wave + rep*4;
            const int ub  = ci*128 + ntl*16;
            bf16x8 bw[3];
            #pragma unroll
            for (int kk = 0; kk < 3; ++kk)
                bw[kk] = *(const bf16x8*)(wfc1 + (size_t)(ub + l16)*96 + kk*32 + quad*8);
            const f32x4 b4 = *(const f32x4*)&fc1b[ub + quad*4];
            #pragma unroll
            for (int mt = 0; mt < 4; ++mt) {
                f32x4 acc = {};
                #pragma unroll
                for (int kk = 0; kk < 3; ++kk) acc = mfma16(bw[kk], af2[mt][kk], acc);
                bf16x4 g4;
                #pragma unroll
                for (int r = 0; r < 4; ++r) {
                    // gelu(x) = x * sigmoid(1.5957691x + 0.0713548x^3)
                    float tv = acc[r] + b4[r];
                    float uu = tv*tv;
                    float w  = tv*fmaf(-0.0713548165f, uu, -1.5957691216f);
                    float e  = __expf(w);
                    g4[r] = (bf16)(tv*__builtin_amdgcn_rcpf(1.f + e));
                }
                *(bf16x4*)&sm[MYG_E + (mt*16 + l16)*136 + ntl*16 + quad*4] = g4;
            }
        }
        __syncthreads();
        bf16x8 ag[4];
        #pragma unroll
        for (int kq = 0; kq < 4; ++kq)
            ag[kq] = *(const bf16x8*)&sm[MYG_E + (wave*16+l16)*136 + kq*32 + quad*8];
        #pragma unroll
        for (int nt2 = 0; nt2 < 6; ++nt2) {
            const int c = nt2*16 + l16;
            #pragma unroll
            for (int kq = 0; kq < 4; ++kq) {
                bf16x8 bw = *(const bf16x8*)(wfc2 + (size_t)c*384 + ci*128 + kq*32 + quad*8);
                acc2[nt2] = mfma16(ag[kq], bw, acc2[nt2]);
            }
        }
        if (ci < 2) __syncthreads();   // G rewritten next chunk
    }

    // ---- out = h + mlp (+fc2b); h from AXO; direct NCHW f32x4 store ----
    {
        const int row = wave*16 + quad*4;             // 4 consecutive window tokens, same row
        const int gh  = (wh*WS_ + (row>>3) + SHIFT_) & (H_-1);
        const int gw0 = (ww*WS_ + (row&7)  + SHIFT_) & (W_-1);   // 4-aligned
        #pragma unroll
        for (int nt2 = 0; nt2 < 6; ++nt2) {
            const int c = nt2*16 + l16;
            const float bias = fc2b[c];
            f32x4 o;
            #pragma unroll
            for (int r = 0; r < 4; ++r)
                o[r] = acc2[nt2][r] + bias + (float)sm[AXO_E + (row+r)*104 + c];
            *(f32x4*)(out + (size_t)(b*96 + c)*HW_ + gh*W_ + gw0) = o;
        }
    }
}

extern "C" void kernel_launch(void* const* d_in, const int* in_sizes, int n_in,
                              void* d_out, int out_size, void* d_ws, size_t ws_size,
                              hipStream_t stream) {
    const float* x      = (const float*)d_in[0];
    const float* norm_w = (const float*)d_in[1];
    const float* norm_b = (const float*)d_in[2];
    const float* qkv_w  = (const float*)d_in[3];
    const float* qkv_b  = (const float*)d_in[4];
    const float* proj_w = (const float*)d_in[5];
    const float* proj_b = (const float*)d_in[6];
    const float* rpb    = (const float*)d_in[7];
    const float* n2w    = (const float*)d_in[8];
    const float* n2b    = (const float*)d_in[9];
    const float* fc1w   = (const float*)d_in[10];
    const float* fc1b   = (const float*)d_in[11];
    const float* fc2w   = (const float*)d_in[12];
    const float* fc2b   = (const float*)d_in[13];

    float* outp = (float*)d_out;
    char*  ws   = (char*)d_ws;
    bf16*  wa   = (bf16*)ws;                         // weight arena
    float* bq2  = (float*)(ws + (size_t)WSUM_E*2);

    prepw_kernel<<<WBLKS, 256, 0, stream>>>(qkv_w, qkv_b, proj_w, fc1w, fc2w, wa, bq2);
    fused_kernel<<<B_*1024, 256, 0, stream>>>(x, norm_w, norm_b,
                                              wa, bq2,
                                              wa + WQ2_E, proj_b, rpb,
                                              n2w, n2b,
                                              wa + WQ2_E + WPR_E, fc1b,
                                              wa + WQ2_E + WPR_E + WF1_E, fc2b,
                                              outp);
}